// Round 13
// baseline (572.414 us; speedup 1.0000x reference)
//
#include <hip/hip_runtime.h>

// Problem constants (B=4, T=8, N=2048, C=64)
#define BB 4
#define TT 8
#define NN 2048
#define CC 64
#define MM 512           // N / SPATIAL_STRIDE
#define KK 32
#define H3DIM 256
#define RAD2 0.25f
#define FINF 3.4e38f

typedef _Float16 f16x8 __attribute__((ext_vector_type(8)));
typedef _Float16 f16x4 __attribute__((ext_vector_type(4)));
typedef float f32x4 __attribute__((ext_vector_type(4)));

// ---------------------------------------------------------------------------
// f32 DPP wave-64 max tree (row_shr 1/2/4/8 + row_bcast15/31, result lane 63).
// HW-validated rounds 2-11.
// ---------------------------------------------------------------------------
template <int CTRL>
__device__ __forceinline__ float dpp_max_step(float x) {
    int xi = __builtin_bit_cast(int, x);
    int yi = __builtin_amdgcn_update_dpp(xi, xi, CTRL, 0xf, 0xf, false);
    return fmaxf(x, __builtin_bit_cast(float, yi));
}
__device__ __forceinline__ float wave_max64(float x) {
    x = dpp_max_step<0x111>(x);
    x = dpp_max_step<0x112>(x);
    x = dpp_max_step<0x114>(x);
    x = dpp_max_step<0x118>(x);
    x = dpp_max_step<0x142>(x);
    x = dpp_max_step<0x143>(x);
    return __builtin_bit_cast(float, __builtin_amdgcn_readlane(__builtin_bit_cast(int, x), 63));
}
// Packed u64 DPP min (validated rounds 8-12 in k_knn).
template <int CTRL>
__device__ __forceinline__ unsigned long long dpp_minkey_step(unsigned long long k) {
    int lo = (int)(unsigned)k;
    int hi = (int)(unsigned)(k >> 32);
    int slo = __builtin_amdgcn_update_dpp(lo, lo, CTRL, 0xf, 0xf, false);
    int shi = __builtin_amdgcn_update_dpp(hi, hi, CTRL, 0xf, 0xf, false);
    unsigned long long s = ((unsigned long long)(unsigned)shi << 32) | (unsigned)slo;
    return s < k ? s : k;
}
__device__ __forceinline__ unsigned long long wave_minkey(unsigned long long k) {
    k = dpp_minkey_step<0x111>(k);
    k = dpp_minkey_step<0x112>(k);
    k = dpp_minkey_step<0x114>(k);
    k = dpp_minkey_step<0x118>(k);
    k = dpp_minkey_step<0x142>(k);
    k = dpp_minkey_step<0x143>(k);
    int lo = __builtin_amdgcn_readlane((int)(unsigned)k, 63);
    int hi = __builtin_amdgcn_readlane((int)(unsigned)(k >> 32), 63);
    return ((unsigned long long)(unsigned)hi << 32) | (unsigned)lo;
}

// ---------------------------------------------------------------------------
// Fused kernel 1: FPS (blocks 0..31) + P' (blocks 32..1055).
// (unchanged from round 11 — verified, 245 us)
// ---------------------------------------------------------------------------
#define FPP_LDS 52224   // max(fps: 24640, pp: 68*128*4 + 64*68*4 = 52224)

__global__ __launch_bounds__(256) void k_fps_pp(const float* __restrict__ xyzs,
                                                const float* __restrict__ feats,
                                                const float* __restrict__ w1,
                                                int* __restrict__ fps_idx,
                                                _Float16* __restrict__ Pp) {
    extern __shared__ char fsm[];
    int tid = threadIdx.x;

    if (blockIdx.x < BB * TT) {
        // ------------------------- FPS branch (round-5 verbatim) -----------
        float* sx = (float*)fsm;
        float* sy = sx + NN;
        float* sz = sy + NN;
        float* pd = sz + NN;            // [2][4]
        int* pi = (int*)(pd + 8);       // [2][4]
        int bt = blockIdx.x;
        int lane = tid & 63, w = tid >> 6;
        const float* src = xyzs + (size_t)bt * NN * 3;
        for (int i = tid; i < NN; i += 256) {
            sx[i] = src[i * 3 + 0];
            sy[i] = src[i * 3 + 1];
            sz[i] = src[i * 3 + 2];
        }
        __syncthreads();

        float px[8], py[8], pz[8], dist[8];
#pragma unroll
        for (int j = 0; j < 8; ++j) {
            int p = tid * 8 + j;
            px[j] = sx[p]; py[j] = sy[p]; pz[j] = sz[p];
            dist[j] = 1e10f;
        }

        int cur = 0;
        if (tid == 0) fps_idx[bt * MM + 0] = 0;
        int pbase = tid * 8;

        for (int it = 1; it < MM; ++it) {
            float cx = sx[cur], cy = sy[cur], cz = sz[cur];   // broadcast reads
            float bestd = -1.0f;
            int bestp = 0;
#pragma unroll
            for (int j = 0; j < 8; ++j) {
                float dx = px[j] - cx, dy = py[j] - cy, dz = pz[j] - cz;
                float d = dx * dx + dy * dy + dz * dz;
                float nd = fminf(dist[j], d);
                dist[j] = nd;
                if (nd > bestd) { bestd = nd; bestp = pbase + j; }  // strict > keeps smallest j
            }
            float wmax = wave_max64(bestd);
            unsigned long long mask = __ballot(bestd == wmax);
            int wl = __ffsll(mask) - 1;
            int wbp = __builtin_amdgcn_readlane(bestp, wl);
            if (lane == 0) { pd[(it & 1) * 4 + w] = wmax; pi[(it & 1) * 4 + w] = wbp; }
            __syncthreads();
            float bd = pd[(it & 1) * 4 + 0];
            int bp = pi[(it & 1) * 4 + 0];
#pragma unroll
            for (int q = 1; q < 4; ++q) {
                float d2 = pd[(it & 1) * 4 + q];
                int p2 = pi[(it & 1) * 4 + q];
                if (d2 > bd) { bd = d2; bp = p2; }   // strict > : earlier wave wins ties
            }
            cur = bp;
            if (tid == 0) fps_idx[bt * MM + it] = cur;
        }
    } else {
        // ------------------------- P' branch (round-9 k_pp verbatim) -------
        float* sw = (float*)fsm;              // 68*128
        float* sin_ = sw + 68 * 128;          // 64*68
        for (int i = tid; i < 68 * 128; i += 256) {
            int r = i >> 7, c = i & 127;
            float v = 0.f;
            if (r < 64) v = w1[r * 128 + c];
            else if (r < 67) v = w1[(128 + r - 64) * 128 + c];
            sw[i] = v;
        }
        int row0 = (blockIdx.x - BB * TT) * 64;
        int bt = row0 >> 11;
        int b = bt >> 3, t = bt & 7;
        int tn = (t + 1 < TT) ? (t + 1) : (TT - 1);
        size_t nbase = (size_t)(b * TT + tn) * NN + (row0 & (NN - 1));
        const float* fsrc = feats + nbase * CC;
        const float* xsrc = xyzs + nbase * 3;
        for (int i = tid; i < 1024; i += 256) {
            float4 v = ((const float4*)fsrc)[i];
            int r = i >> 4, c = (i & 15) * 4;
            *(float4*)&sin_[r * 68 + c] = v;
        }
        if (tid < 192) {
            int r = tid / 3, c = tid - r * 3;
            sin_[r * 68 + 64 + c] = xsrc[tid];
        }
        if (tid < 64) sin_[tid * 68 + 67] = 0.f;
        __syncthreads();

        int rowg = tid >> 5, colg = tid & 31;
        float4 acc[8];
#pragma unroll
        for (int i = 0; i < 8; ++i) acc[i] = make_float4(0.f, 0.f, 0.f, 0.f);
        for (int k = 0; k < 68; k += 4) {
            float4 a4[8], b4[4];
#pragma unroll
            for (int i = 0; i < 8; ++i) a4[i] = *(const float4*)&sin_[(rowg * 8 + i) * 68 + k];
#pragma unroll
            for (int kk = 0; kk < 4; ++kk) b4[kk] = *(const float4*)&sw[(k + kk) * 128 + colg * 4];
#pragma unroll
            for (int i = 0; i < 8; ++i) {
#pragma unroll
                for (int kk = 0; kk < 4; ++kk) {
                    float av = (kk == 0) ? a4[i].x : (kk == 1) ? a4[i].y : (kk == 2) ? a4[i].z : a4[i].w;
                    acc[i].x += av * b4[kk].x;
                    acc[i].y += av * b4[kk].y;
                    acc[i].z += av * b4[kk].z;
                    acc[i].w += av * b4[kk].w;
                }
            }
        }
#pragma unroll
        for (int i = 0; i < 8; ++i) {
            f16x4 h;
            h[0] = (_Float16)acc[i].x; h[1] = (_Float16)acc[i].y;
            h[2] = (_Float16)acc[i].z; h[3] = (_Float16)acc[i].w;
            *(f16x4*)&Pp[(size_t)(row0 + rowg * 8 + i) * 128 + colg * 4] = h;
        }
    }
}

// ---------------------------------------------------------------------------
// Kernel 2b: Q' + anchors. (unchanged — verified)
// ---------------------------------------------------------------------------
__global__ __launch_bounds__(256) void k_qp(const float* __restrict__ xyzs,
                                            const float* __restrict__ feats,
                                            const float* __restrict__ w1,
                                            const float* __restrict__ b1,
                                            const int* __restrict__ fps_idx,
                                            float* __restrict__ Qp,
                                            float* __restrict__ out_anchor) {
    __shared__ float sw[68 * 128];
    __shared__ float sin_[64 * 68];
    __shared__ float sb[128];
    int tid = threadIdx.x;
    for (int i = tid; i < 68 * 128; i += 256) {
        int r = i >> 7, c = i & 127;
        float v = 0.f;
        if (r < 64) v = w1[(64 + r) * 128 + c];
        else if (r < 67) v = w1[(128 + r - 64) * 128 + c];
        sw[i] = v;
    }
    if (tid < 128) sb[tid] = b1[tid];
    int row0 = blockIdx.x * 64;
    int bt = row0 >> 9;
    size_t fbase = (size_t)bt * NN;
    {
        int r = tid >> 2, seg = tid & 3;
        int aidx = fps_idx[row0 + r];
        const float4* fr = (const float4*)(feats + (fbase + aidx) * CC);
#pragma unroll
        for (int i = 0; i < 4; ++i) {
            float4 v = fr[seg * 4 + i];
            *(float4*)&sin_[r * 68 + seg * 16 + i * 4] = v;
        }
    }
    if (tid < 64) {
        int aidx = fps_idx[row0 + tid];
        const float* xs = xyzs + (fbase + aidx) * 3;
        float x = xs[0], y = xs[1], z = xs[2];
        sin_[tid * 68 + 64] = -x;
        sin_[tid * 68 + 65] = -y;
        sin_[tid * 68 + 66] = -z;
        sin_[tid * 68 + 67] = 0.f;
        out_anchor[(size_t)(row0 + tid) * 3 + 0] = x;
        out_anchor[(size_t)(row0 + tid) * 3 + 1] = y;
        out_anchor[(size_t)(row0 + tid) * 3 + 2] = z;
    }
    __syncthreads();

    int rowg = tid >> 5, colg = tid & 31;
    float4 bias = *(const float4*)&sb[colg * 4];
    float4 acc[8];
#pragma unroll
    for (int i = 0; i < 8; ++i) acc[i] = bias;
    for (int k = 0; k < 68; k += 4) {
        float4 a4[8], b4[4];
#pragma unroll
        for (int i = 0; i < 8; ++i) a4[i] = *(const float4*)&sin_[(rowg * 8 + i) * 68 + k];
#pragma unroll
        for (int kk = 0; kk < 4; ++kk) b4[kk] = *(const float4*)&sw[(k + kk) * 128 + colg * 4];
#pragma unroll
        for (int i = 0; i < 8; ++i) {
#pragma unroll
            for (int kk = 0; kk < 4; ++kk) {
                float av = (kk == 0) ? a4[i].x : (kk == 1) ? a4[i].y : (kk == 2) ? a4[i].z : a4[i].w;
                acc[i].x += av * b4[kk].x;
                acc[i].y += av * b4[kk].y;
                acc[i].z += av * b4[kk].z;
                acc[i].w += av * b4[kk].w;
            }
        }
    }
#pragma unroll
    for (int i = 0; i < 8; ++i)
        *(float4*)&Qp[(size_t)(row0 + rowg * 8 + i) * 128 + colg * 4] = acc[i];
}

// ---------------------------------------------------------------------------
// Kernel 3: exact stable top-K=32 nearest + radius filter.
// NEW: the wave's two anchors are processed INTERLEAVED (independent register
// sets, one round loop) so their rescan/DPP-tree chains overlap. Per-anchor
// operation sequence, tie-breaks, and radius rule are identical to rounds
// 8-12 -> bit-identical idxk.
// ---------------------------------------------------------------------------
__global__ __launch_bounds__(256) void k_knn(const float* __restrict__ xyzs,
                                             const int* __restrict__ fps_idx,
                                             int* __restrict__ idxk) {
    __shared__ float sx[NN], sy[NN], sz[NN];
    int tid = threadIdx.x;
    int wave = tid >> 6, lane = tid & 63;
    int bt = blockIdx.x >> 6;              // 64 blocks per (b,t)
    int sub = blockIdx.x & 63;
    int b = bt >> 3, t = bt & 7;
    int tn = (t + 1 < TT) ? (t + 1) : (TT - 1);
    const float* src = xyzs + ((size_t)(b * TT + tn)) * NN * 3;
    for (int i = tid; i < NN; i += 256) {
        sx[i] = src[i * 3 + 0];
        sy[i] = src[i * 3 + 1];
        sz[i] = src[i * 3 + 2];
    }
    __syncthreads();

    int mrowA = bt * MM + sub * 8 + wave * 2;
    int mrowB = mrowA + 1;
    int aidxA = fps_idx[mrowA];
    int aidxB = fps_idx[mrowB];
    const float* xsA = xyzs + ((size_t)bt * NN + aidxA) * 3;   // frame t itself
    const float* xsB = xyzs + ((size_t)bt * NN + aidxB) * 3;
    float axA = xsA[0], ayA = xsA[1], azA = xsA[2];
    float axB = xsB[0], ayB = xsB[1], azB = xsB[2];

    float dA[32], dB[32];
#pragma unroll
    for (int j = 0; j < 32; ++j) {
        int p = j * 64 + lane;
        float x = sx[p], y = sy[p], z = sz[p];
        float dxA = x - axA, dyA = y - ayA, dzA = z - azA;
        dA[j] = dxA * dxA + dyA * dyA + dzA * dzA;
        float dxB = x - axB, dyB = y - ayB, dzB = z - azB;
        dB[j] = dxB * dxB + dyB * dyB + dzB * dzB;
    }

    int p0A = 0, myA = 0, p0B = 0, myB = 0;
    for (int r = 0; r < KK; ++r) {
        // ---- rescan + 3-node tree, anchor A ----
        float gdA[4]; int gpA[4];
#pragma unroll
        for (int g = 0; g < 4; ++g) {
            gdA[g] = dA[g * 8];
            gpA[g] = (g * 8) * 64 + lane;
#pragma unroll
            for (int jj = 1; jj < 8; ++jj) {
                float dj = dA[g * 8 + jj];
                if (dj < gdA[g]) { gdA[g] = dj; gpA[g] = (g * 8 + jj) * 64 + lane; }  // strict <
            }
        }
        bool uA01 = gdA[1] < gdA[0], uA23 = gdA[3] < gdA[2];
        float daA = uA01 ? gdA[1] : gdA[0], dbA = uA23 ? gdA[3] : gdA[2];
        int paA = uA01 ? gpA[1] : gpA[0], pbA = uA23 ? gpA[3] : gpA[2];
        bool ufA = dbA < daA;
        float bdA = ufA ? dbA : daA;
        int bpA = ufA ? pbA : paA;
        // ---- rescan + tree, anchor B (independent chain) ----
        float gdB[4]; int gpB[4];
#pragma unroll
        for (int g = 0; g < 4; ++g) {
            gdB[g] = dB[g * 8];
            gpB[g] = (g * 8) * 64 + lane;
#pragma unroll
            for (int jj = 1; jj < 8; ++jj) {
                float dj = dB[g * 8 + jj];
                if (dj < gdB[g]) { gdB[g] = dj; gpB[g] = (g * 8 + jj) * 64 + lane; }
            }
        }
        bool uB01 = gdB[1] < gdB[0], uB23 = gdB[3] < gdB[2];
        float daB = uB01 ? gdB[1] : gdB[0], dbB = uB23 ? gdB[3] : gdB[2];
        int paB = uB01 ? gpB[1] : gpB[0], pbB = uB23 ? gpB[3] : gpB[2];
        bool ufB = dbB < daB;
        float bdB = ufB ? dbB : daB;
        int bpB = ufB ? pbB : paB;

        // ---- wave-min packed keys (two independent DPP trees) ----
        unsigned long long keyA =
            ((unsigned long long)(unsigned)__builtin_bit_cast(unsigned, bdA) << 32) | (unsigned)bpA;
        unsigned long long keyB =
            ((unsigned long long)(unsigned)__builtin_bit_cast(unsigned, bdB) << 32) | (unsigned)bpB;
        unsigned long long wkA = wave_minkey(keyA);
        unsigned long long wkB = wave_minkey(keyB);
        int pstarA = (int)(unsigned)wkA;
        float dstarA = __builtin_bit_cast(float, (unsigned)(wkA >> 32));
        int pstarB = (int)(unsigned)wkB;
        float dstarB = __builtin_bit_cast(float, (unsigned)(wkB >> 32));

        if (r == 0) { p0A = pstarA; myA = pstarA; p0B = pstarB; myB = pstarB; }
        int outpA = (dstarA <= RAD2) ? pstarA : p0A;   // radius replacement
        int outpB = (dstarB <= RAD2) ? pstarB : p0B;
        if (lane == r) { myA = outpA; myB = outpB; }

        if (r < KK - 1) {
            int lanewA = pstarA & 63, jwA = pstarA >> 6;    // uniform (SGPR)
            bool imwA = (lane == lanewA);
#pragma unroll
            for (int j = 0; j < 32; ++j)
                dA[j] = (imwA && j == jwA) ? FINF : dA[j];
            int lanewB = pstarB & 63, jwB = pstarB >> 6;
            bool imwB = (lane == lanewB);
#pragma unroll
            for (int j = 0; j < 32; ++j)
                dB[j] = (imwB && j == jwB) ? FINF : dB[j];
        }
    }
    if (lane < KK) {
        idxk[(size_t)mrowA * KK + lane] = myA;
        idxk[(size_t)mrowB * KK + lane] = myB;
    }
}

// ---------------------------------------------------------------------------
// Kernel 4: persistent-block fp16 MFMA MLP (layers 2+3) + max over K.
// (unchanged from round 12 — verified; 1024 thr / 16 waves)
// ---------------------------------------------------------------------------
#define SM_W2 0
#define SM_W3 32768
#define SM_H1 98304
#define SM_H2 114688
#define SM_B2 131072
#define SM_B3 131584
#define SM_TOTAL 132608

__global__ __launch_bounds__(1024, 1) void k_mlp(const _Float16* __restrict__ Pp,
                                                 const float* __restrict__ Qp,
                                                 const int* __restrict__ idxk,
                                                 const float* __restrict__ w2,
                                                 const float* __restrict__ b2,
                                                 const float* __restrict__ w3,
                                                 const float* __restrict__ b3,
                                                 float* __restrict__ out_feat) {
    extern __shared__ char smem[];
    int tid = threadIdx.x;
    int bid = blockIdx.x;                  // 0..255

    for (int i = tid; i < 128 * 128; i += 1024) {
        int n = i & 127, kk = i >> 7;
        _Float16 v = (_Float16)w2[kk * 128 + n];
        *(_Float16*)(smem + SM_W2 + n * 256 + ((2 * kk) ^ ((n & 7) << 4))) = v;
    }
    for (int i = tid; i < 256 * 128; i += 1024) {
        int n = i & 255, kk = i >> 8;
        _Float16 v = (_Float16)w3[kk * 256 + n];
        *(_Float16*)(smem + SM_W3 + n * 256 + ((2 * kk) ^ ((n & 7) << 4))) = v;
    }
    if (tid < 128) *(float*)(smem + SM_B2 + tid * 4) = b2[tid];
    if (tid < 256) *(float*)(smem + SM_B3 + tid * 4) = b3[tid];
    __syncthreads();

    int lane = tid & 63;
    int w = tid >> 6;                      // 0..15
    int wm = w >> 3, wn = w & 7;           // 2 anchors x 8 col-groups
    int l15 = lane & 15, g = lane >> 4;
    int hswz = (l15 & 7) << 4;

    const f32x4 zero4 = {0.f, 0.f, 0.f, 0.f};

    for (int c = 0; c < 32; ++c) {
        int a0 = bid * 64 + c * 2;
        int bt = a0 >> 9;

        // ---- build h1: 64 rows x 16 segments of 8 fp16, one f16x8/thread ----
        {
            int r = tid >> 4, seg = tid & 15;
            int arow = a0 + (r >> 5);
            int kidx = r & 31;
            int nk = idxk[(size_t)arow * KK + kidx];
            const _Float16* ps = Pp + ((size_t)(bt * NN + nk)) * 128 + seg * 8;
            const float* qs = Qp + (size_t)arow * 128 + seg * 8;
            int rowbase = SM_H1 + r * 256;
            int swz = (r & 7) << 4;
            f16x8 pv = *(const f16x8*)ps;
            f32x4 q0 = *(const f32x4*)qs;
            f32x4 q1 = *(const f32x4*)(qs + 4);
            f16x8 hv;
#pragma unroll
            for (int j = 0; j < 4; ++j) hv[j] = (_Float16)fmaxf((float)pv[j] + q0[j], 0.f);
#pragma unroll
            for (int j = 0; j < 4; ++j) hv[4 + j] = (_Float16)fmaxf((float)pv[4 + j] + q1[j], 0.f);
            *(f16x8*)(smem + rowbase + ((seg * 16) ^ swz)) = hv;
        }
        __syncthreads();

        // ---- layer 2: wave tile 32 rows x 16 cols ----
        f32x4 acc2[2];
#pragma unroll
        for (int m = 0; m < 2; ++m) acc2[m] = zero4;

#pragma unroll
        for (int ks = 0; ks < 4; ++ks) {
            int kbyte = ks * 64 + g * 16;
            f16x8 af[2], bf;
#pragma unroll
            for (int m = 0; m < 2; ++m) {
                int row = wm * 32 + m * 16 + l15;
                af[m] = *(const f16x8*)(smem + SM_H1 + row * 256 + (kbyte ^ hswz));
            }
            {
                int col = wn * 16 + l15;
                bf = *(const f16x8*)(smem + SM_W2 + col * 256 + (kbyte ^ hswz));
            }
#pragma unroll
            for (int m = 0; m < 2; ++m)
                acc2[m] = __builtin_amdgcn_mfma_f32_16x16x32_f16(af[m], bf, acc2[m], 0, 0, 0);
        }
#pragma unroll
        for (int m = 0; m < 2; ++m) {
            int col = wn * 16 + l15;
            float bb = *(const float*)(smem + SM_B2 + col * 4);
#pragma unroll
            for (int r = 0; r < 4; ++r) {
                int row = wm * 32 + m * 16 + g * 4 + r;
                float v = fmaxf(acc2[m][r] + bb, 0.f);
                *(_Float16*)(smem + SM_H2 + row * 256 + ((2 * col) ^ ((row & 7) << 4))) = (_Float16)v;
            }
        }
        __syncthreads();

        // ---- layer 3: wave tile 32 rows x 32 cols; max over K fused ----
        f32x4 acc3[2][2];
#pragma unroll
        for (int m = 0; m < 2; ++m)
#pragma unroll
            for (int n = 0; n < 2; ++n) acc3[m][n] = zero4;

#pragma unroll
        for (int ks = 0; ks < 4; ++ks) {
            int kbyte = ks * 64 + g * 16;
            f16x8 af[2], bf[2];
#pragma unroll
            for (int m = 0; m < 2; ++m) {
                int row = wm * 32 + m * 16 + l15;
                af[m] = *(const f16x8*)(smem + SM_H2 + row * 256 + (kbyte ^ hswz));
            }
#pragma unroll
            for (int n = 0; n < 2; ++n) {
                int col = wn * 32 + n * 16 + l15;
                bf[n] = *(const f16x8*)(smem + SM_W3 + col * 256 + (kbyte ^ hswz));
            }
#pragma unroll
            for (int m = 0; m < 2; ++m)
#pragma unroll
                for (int n = 0; n < 2; ++n)
                    acc3[m][n] = __builtin_amdgcn_mfma_f32_16x16x32_f16(af[m], bf[n], acc3[m][n], 0, 0, 0);
        }
#pragma unroll
        for (int n = 0; n < 2; ++n) {
            int col = wn * 32 + n * 16 + l15;
            float s = acc3[0][n][0];
#pragma unroll
            for (int r = 1; r < 4; ++r) s = fmaxf(s, acc3[0][n][r]);
#pragma unroll
            for (int r = 0; r < 4; ++r) s = fmaxf(s, acc3[1][n][r]);
            s = fmaxf(s, __shfl_xor(s, 16));
            s = fmaxf(s, __shfl_xor(s, 32));
            if (g == 0) {
                float bb = *(const float*)(smem + SM_B3 + col * 4);
                out_feat[(size_t)(a0 + wm) * H3DIM + col] = fmaxf(s + bb, 0.f);
            }
        }
        __syncthreads();
    }
}

// ---------------------------------------------------------------------------
extern "C" void kernel_launch(void* const* d_in, const int* in_sizes, int n_in,
                              void* d_out, int out_size, void* d_ws, size_t ws_size,
                              hipStream_t stream) {
    const float* xyzs  = (const float*)d_in[0];
    const float* feats = (const float*)d_in[1];
    const float* w1 = (const float*)d_in[2];
    const float* b1 = (const float*)d_in[3];
    const float* w2 = (const float*)d_in[4];
    const float* b2 = (const float*)d_in[5];
    const float* w3 = (const float*)d_in[6];
    const float* b3 = (const float*)d_in[7];

    float* out_anchor = (float*)d_out;
    float* out_feat = out_anchor + (size_t)BB * TT * MM * 3;

    char* ws = (char*)d_ws;
    int* fps_idx = (int*)ws;                                   // 64 KB
    int* idxk = (int*)(ws + 65536);                            // 2 MB
    _Float16* Pp = (_Float16*)(ws + 65536 + 2097152);          // B*T*N*128 fp16 = 16 MB
    float* Qp = (float*)(ws + 65536 + 2097152 + 16777216);     // B*T*M*128 fp32 = 8 MB
    if (ws_size < (size_t)(65536 + 2097152 + 16777216) + (size_t)BB * TT * MM * 128 * 4)
        return;

    (void)hipFuncSetAttribute((const void*)k_fps_pp, hipFuncAttributeMaxDynamicSharedMemorySize, FPP_LDS);
    k_fps_pp<<<BB * TT + BB * TT * NN / 64, 256, FPP_LDS, stream>>>(xyzs, feats, w1, fps_idx, Pp);
    k_knn<<<BB * TT * 64, 256, 0, stream>>>(xyzs, fps_idx, idxk);
    k_qp<<<BB * TT * MM / 64, 256, 0, stream>>>(xyzs, feats, w1, b1, fps_idx, Qp, out_anchor);

    (void)hipFuncSetAttribute((const void*)k_mlp, hipFuncAttributeMaxDynamicSharedMemorySize, SM_TOTAL);
    k_mlp<<<256, 1024, SM_TOTAL, stream>>>(Pp, Qp, idxk, w2, b2, w3, b3, out_feat);
}

// Round 15
// 529.211 us; speedup vs baseline: 1.0816x; 1.0816x over previous
//
#include <hip/hip_runtime.h>

// Problem constants (B=4, T=8, N=2048, C=64)
#define BB 4
#define TT 8
#define NN 2048
#define CC 64
#define MM 512           // N / SPATIAL_STRIDE
#define KK 32
#define H3DIM 256
#define RAD2 0.25f
#define FINF 3.4e38f

typedef _Float16 f16x8 __attribute__((ext_vector_type(8)));
typedef _Float16 f16x4 __attribute__((ext_vector_type(4)));
typedef float f32x4 __attribute__((ext_vector_type(4)));

// ---------------------------------------------------------------------------
// f32 DPP wave-64 max tree (row_shr 1/2/4/8 + row_bcast15/31, result lane 63).
// HW-validated rounds 2-13.
// ---------------------------------------------------------------------------
template <int CTRL>
__device__ __forceinline__ float dpp_max_step(float x) {
    int xi = __builtin_bit_cast(int, x);
    int yi = __builtin_amdgcn_update_dpp(xi, xi, CTRL, 0xf, 0xf, false);
    return fmaxf(x, __builtin_bit_cast(float, yi));
}
__device__ __forceinline__ float wave_max64(float x) {
    x = dpp_max_step<0x111>(x);
    x = dpp_max_step<0x112>(x);
    x = dpp_max_step<0x114>(x);
    x = dpp_max_step<0x118>(x);
    x = dpp_max_step<0x142>(x);
    x = dpp_max_step<0x143>(x);
    return __builtin_bit_cast(float, __builtin_amdgcn_readlane(__builtin_bit_cast(int, x), 63));
}
// Packed u64 DPP min (validated rounds 8-13 in k_knn).
template <int CTRL>
__device__ __forceinline__ unsigned long long dpp_minkey_step(unsigned long long k) {
    int lo = (int)(unsigned)k;
    int hi = (int)(unsigned)(k >> 32);
    int slo = __builtin_amdgcn_update_dpp(lo, lo, CTRL, 0xf, 0xf, false);
    int shi = __builtin_amdgcn_update_dpp(hi, hi, CTRL, 0xf, 0xf, false);
    unsigned long long s = ((unsigned long long)(unsigned)shi << 32) | (unsigned)slo;
    return s < k ? s : k;
}
__device__ __forceinline__ unsigned long long wave_minkey(unsigned long long k) {
    k = dpp_minkey_step<0x111>(k);
    k = dpp_minkey_step<0x112>(k);
    k = dpp_minkey_step<0x114>(k);
    k = dpp_minkey_step<0x118>(k);
    k = dpp_minkey_step<0x142>(k);
    k = dpp_minkey_step<0x143>(k);
    int lo = __builtin_amdgcn_readlane((int)(unsigned)k, 63);
    int hi = __builtin_amdgcn_readlane((int)(unsigned)(k >> 32), 63);
    return ((unsigned long long)(unsigned)hi << 32) | (unsigned)lo;
}

// ---------------------------------------------------------------------------
// Fused kernel 1: FPS (blocks 0..31) + P' (blocks 32..1055).
// (unchanged from round 11 — verified, 245 us)
// ---------------------------------------------------------------------------
#define FPP_LDS 52224   // max(fps: 24640, pp: 68*128*4 + 64*68*4 = 52224)

__global__ __launch_bounds__(256) void k_fps_pp(const float* __restrict__ xyzs,
                                                const float* __restrict__ feats,
                                                const float* __restrict__ w1,
                                                int* __restrict__ fps_idx,
                                                _Float16* __restrict__ Pp) {
    extern __shared__ char fsm[];
    int tid = threadIdx.x;

    if (blockIdx.x < BB * TT) {
        // ------------------------- FPS branch (round-5 verbatim) -----------
        float* sx = (float*)fsm;
        float* sy = sx + NN;
        float* sz = sy + NN;
        float* pd = sz + NN;            // [2][4]
        int* pi = (int*)(pd + 8);       // [2][4]
        int bt = blockIdx.x;
        int lane = tid & 63, w = tid >> 6;
        const float* src = xyzs + (size_t)bt * NN * 3;
        for (int i = tid; i < NN; i += 256) {
            sx[i] = src[i * 3 + 0];
            sy[i] = src[i * 3 + 1];
            sz[i] = src[i * 3 + 2];
        }
        __syncthreads();

        float px[8], py[8], pz[8], dist[8];
#pragma unroll
        for (int j = 0; j < 8; ++j) {
            int p = tid * 8 + j;
            px[j] = sx[p]; py[j] = sy[p]; pz[j] = sz[p];
            dist[j] = 1e10f;
        }

        int cur = 0;
        if (tid == 0) fps_idx[bt * MM + 0] = 0;
        int pbase = tid * 8;

        for (int it = 1; it < MM; ++it) {
            float cx = sx[cur], cy = sy[cur], cz = sz[cur];   // broadcast reads
            float bestd = -1.0f;
            int bestp = 0;
#pragma unroll
            for (int j = 0; j < 8; ++j) {
                float dx = px[j] - cx, dy = py[j] - cy, dz = pz[j] - cz;
                float d = dx * dx + dy * dy + dz * dz;
                float nd = fminf(dist[j], d);
                dist[j] = nd;
                if (nd > bestd) { bestd = nd; bestp = pbase + j; }  // strict > keeps smallest j
            }
            float wmax = wave_max64(bestd);
            unsigned long long mask = __ballot(bestd == wmax);
            int wl = __ffsll(mask) - 1;
            int wbp = __builtin_amdgcn_readlane(bestp, wl);
            if (lane == 0) { pd[(it & 1) * 4 + w] = wmax; pi[(it & 1) * 4 + w] = wbp; }
            __syncthreads();
            float bd = pd[(it & 1) * 4 + 0];
            int bp = pi[(it & 1) * 4 + 0];
#pragma unroll
            for (int q = 1; q < 4; ++q) {
                float d2 = pd[(it & 1) * 4 + q];
                int p2 = pi[(it & 1) * 4 + q];
                if (d2 > bd) { bd = d2; bp = p2; }   // strict > : earlier wave wins ties
            }
            cur = bp;
            if (tid == 0) fps_idx[bt * MM + it] = cur;
        }
    } else {
        // ------------------------- P' branch (round-9 k_pp verbatim) -------
        float* sw = (float*)fsm;              // 68*128
        float* sin_ = sw + 68 * 128;          // 64*68
        for (int i = tid; i < 68 * 128; i += 256) {
            int r = i >> 7, c = i & 127;
            float v = 0.f;
            if (r < 64) v = w1[r * 128 + c];
            else if (r < 67) v = w1[(128 + r - 64) * 128 + c];
            sw[i] = v;
        }
        int row0 = (blockIdx.x - BB * TT) * 64;
        int bt = row0 >> 11;
        int b = bt >> 3, t = bt & 7;
        int tn = (t + 1 < TT) ? (t + 1) : (TT - 1);
        size_t nbase = (size_t)(b * TT + tn) * NN + (row0 & (NN - 1));
        const float* fsrc = feats + nbase * CC;
        const float* xsrc = xyzs + nbase * 3;
        for (int i = tid; i < 1024; i += 256) {
            float4 v = ((const float4*)fsrc)[i];
            int r = i >> 4, c = (i & 15) * 4;
            *(float4*)&sin_[r * 68 + c] = v;
        }
        if (tid < 192) {
            int r = tid / 3, c = tid - r * 3;
            sin_[r * 68 + 64 + c] = xsrc[tid];
        }
        if (tid < 64) sin_[tid * 68 + 67] = 0.f;
        __syncthreads();

        int rowg = tid >> 5, colg = tid & 31;
        float4 acc[8];
#pragma unroll
        for (int i = 0; i < 8; ++i) acc[i] = make_float4(0.f, 0.f, 0.f, 0.f);
        for (int k = 0; k < 68; k += 4) {
            float4 a4[8], b4[4];
#pragma unroll
            for (int i = 0; i < 8; ++i) a4[i] = *(const float4*)&sin_[(rowg * 8 + i) * 68 + k];
#pragma unroll
            for (int kk = 0; kk < 4; ++kk) b4[kk] = *(const float4*)&sw[(k + kk) * 128 + colg * 4];
#pragma unroll
            for (int i = 0; i < 8; ++i) {
#pragma unroll
                for (int kk = 0; kk < 4; ++kk) {
                    float av = (kk == 0) ? a4[i].x : (kk == 1) ? a4[i].y : (kk == 2) ? a4[i].z : a4[i].w;
                    acc[i].x += av * b4[kk].x;
                    acc[i].y += av * b4[kk].y;
                    acc[i].z += av * b4[kk].z;
                    acc[i].w += av * b4[kk].w;
                }
            }
        }
#pragma unroll
        for (int i = 0; i < 8; ++i) {
            f16x4 h;
            h[0] = (_Float16)acc[i].x; h[1] = (_Float16)acc[i].y;
            h[2] = (_Float16)acc[i].z; h[3] = (_Float16)acc[i].w;
            *(f16x4*)&Pp[(size_t)(row0 + rowg * 8 + i) * 128 + colg * 4] = h;
        }
    }
}

// ---------------------------------------------------------------------------
// Kernel 2b: Q' + anchors. (unchanged — verified)
// ---------------------------------------------------------------------------
__global__ __launch_bounds__(256) void k_qp(const float* __restrict__ xyzs,
                                            const float* __restrict__ feats,
                                            const float* __restrict__ w1,
                                            const float* __restrict__ b1,
                                            const int* __restrict__ fps_idx,
                                            float* __restrict__ Qp,
                                            float* __restrict__ out_anchor) {
    __shared__ float sw[68 * 128];
    __shared__ float sin_[64 * 68];
    __shared__ float sb[128];
    int tid = threadIdx.x;
    for (int i = tid; i < 68 * 128; i += 256) {
        int r = i >> 7, c = i & 127;
        float v = 0.f;
        if (r < 64) v = w1[(64 + r) * 128 + c];
        else if (r < 67) v = w1[(128 + r - 64) * 128 + c];
        sw[i] = v;
    }
    if (tid < 128) sb[tid] = b1[tid];
    int row0 = blockIdx.x * 64;
    int bt = row0 >> 9;
    size_t fbase = (size_t)bt * NN;
    {
        int r = tid >> 2, seg = tid & 3;
        int aidx = fps_idx[row0 + r];
        const float4* fr = (const float4*)(feats + (fbase + aidx) * CC);
#pragma unroll
        for (int i = 0; i < 4; ++i) {
            float4 v = fr[seg * 4 + i];
            *(float4*)&sin_[r * 68 + seg * 16 + i * 4] = v;
        }
    }
    if (tid < 64) {
        int aidx = fps_idx[row0 + tid];
        const float* xs = xyzs + (fbase + aidx) * 3;
        float x = xs[0], y = xs[1], z = xs[2];
        sin_[tid * 68 + 64] = -x;
        sin_[tid * 68 + 65] = -y;
        sin_[tid * 68 + 66] = -z;
        sin_[tid * 68 + 67] = 0.f;
        out_anchor[(size_t)(row0 + tid) * 3 + 0] = x;
        out_anchor[(size_t)(row0 + tid) * 3 + 1] = y;
        out_anchor[(size_t)(row0 + tid) * 3 + 2] = z;
    }
    __syncthreads();

    int rowg = tid >> 5, colg = tid & 31;
    float4 bias = *(const float4*)&sb[colg * 4];
    float4 acc[8];
#pragma unroll
    for (int i = 0; i < 8; ++i) acc[i] = bias;
    for (int k = 0; k < 68; k += 4) {
        float4 a4[8], b4[4];
#pragma unroll
        for (int i = 0; i < 8; ++i) a4[i] = *(const float4*)&sin_[(rowg * 8 + i) * 68 + k];
#pragma unroll
        for (int kk = 0; kk < 4; ++kk) b4[kk] = *(const float4*)&sw[(k + kk) * 128 + colg * 4];
#pragma unroll
        for (int i = 0; i < 8; ++i) {
#pragma unroll
            for (int kk = 0; kk < 4; ++kk) {
                float av = (kk == 0) ? a4[i].x : (kk == 1) ? a4[i].y : (kk == 2) ? a4[i].z : a4[i].w;
                acc[i].x += av * b4[kk].x;
                acc[i].y += av * b4[kk].y;
                acc[i].z += av * b4[kk].z;
                acc[i].w += av * b4[kk].w;
            }
        }
    }
#pragma unroll
    for (int i = 0; i < 8; ++i)
        *(float4*)&Qp[(size_t)(row0 + rowg * 8 + i) * 128 + colg * 4] = acc[i];
}

// ---------------------------------------------------------------------------
// Kernel 3: exact stable top-K=32 nearest + radius filter.
// Round-12 sequential structure (2 anchors serial/wave, low VGPR) + cached
// group-minima: per round only the winner's group (uniform jw>>3) is
// invalidated + rescanned via a uniform 4-way switch; other 3 groups'
// cached min/argmin reused (identical values — only one slot changed).
// Tie-breaks/radius/order bit-identical to rounds 8-12.
// ---------------------------------------------------------------------------
__global__ __launch_bounds__(256) void k_knn(const float* __restrict__ xyzs,
                                             const int* __restrict__ fps_idx,
                                             int* __restrict__ idxk) {
    __shared__ float sx[NN], sy[NN], sz[NN];
    int tid = threadIdx.x;
    int wave = tid >> 6, lane = tid & 63;
    int bt = blockIdx.x >> 6;              // 64 blocks per (b,t)
    int sub = blockIdx.x & 63;
    int b = bt >> 3, t = bt & 7;
    int tn = (t + 1 < TT) ? (t + 1) : (TT - 1);
    const float* src = xyzs + ((size_t)(b * TT + tn)) * NN * 3;
    for (int i = tid; i < NN; i += 256) {
        sx[i] = src[i * 3 + 0];
        sy[i] = src[i * 3 + 1];
        sz[i] = src[i * 3 + 2];
    }
    __syncthreads();

    for (int a = 0; a < 2; ++a) {
        int mrow = bt * MM + sub * 8 + wave * 2 + a;
        int aidx = fps_idx[mrow];
        const float* xs = xyzs + ((size_t)bt * NN + aidx) * 3;   // frame t itself
        float ax = xs[0], ay = xs[1], az = xs[2];
        float d[32];
#pragma unroll
        for (int j = 0; j < 32; ++j) {
            int p = j * 64 + lane;
            float dx = sx[p] - ax, dy = sy[p] - ay, dz = sz[p] - az;
            d[j] = dx * dx + dy * dy + dz * dz;
        }
        // initial full group scan (identical to previous rounds' per-round scan)
        float gd[4];
        int gp[4];
#pragma unroll
        for (int g = 0; g < 4; ++g) {
            gd[g] = d[g * 8];
            gp[g] = (g * 8) * 64 + lane;
#pragma unroll
            for (int jj = 1; jj < 8; ++jj) {
                float dj = d[g * 8 + jj];
                if (dj < gd[g]) { gd[g] = dj; gp[g] = (g * 8 + jj) * 64 + lane; }  // strict <
            }
        }

        int p0 = 0;
        int myidx = 0;
        for (int r = 0; r < KK; ++r) {
            // 3-node tree over cached group minima (strict < keeps lower group)
            bool u01 = gd[1] < gd[0], u23 = gd[3] < gd[2];
            float da = u01 ? gd[1] : gd[0], db = u23 ? gd[3] : gd[2];
            int pa = u01 ? gp[1] : gp[0], pb = u23 ? gp[3] : gp[2];
            bool uf = db < da;
            float bd = uf ? db : da;
            int bp = uf ? pb : pa;
            // global min via packed key (min d, tie -> min p)
            unsigned long long key =
                ((unsigned long long)(unsigned)__builtin_bit_cast(unsigned, bd) << 32) |
                (unsigned)bp;
            unsigned long long wkey = wave_minkey(key);
            int pstar = (int)(unsigned)wkey;
            float dstar = __builtin_bit_cast(float, (unsigned)(wkey >> 32));
            if (r == 0) { p0 = pstar; myidx = pstar; }
            int outp = (dstar <= RAD2) ? pstar : p0;   // radius replacement
            if (lane == r) myidx = outp;
            if (r < KK - 1) {
                int lanew = pstar & 63;                 // uniform (SGPR)
                int jw = pstar >> 6;                    // uniform slot 0..31
                int gsel = jw >> 3;                     // uniform group 0..3
                int jl = jw & 7;                        // uniform slot-in-group
                bool imw = (lane == lanew);
                // invalidate winner's slot + rescan ONLY that group (uniform branch)
#define KNN_RECOMP(G)                                                         \
                {                                                             \
                    _Pragma("unroll")                                         \
                    for (int jj = 0; jj < 8; ++jj) {                          \
                        float dj = d[(G) * 8 + jj];                           \
                        dj = (imw && jj == jl) ? FINF : dj;                   \
                        d[(G) * 8 + jj] = dj;                                 \
                    }                                                         \
                    gd[G] = d[(G) * 8];                                       \
                    gp[G] = ((G) * 8) * 64 + lane;                            \
                    _Pragma("unroll")                                         \
                    for (int jj = 1; jj < 8; ++jj) {                          \
                        float dj = d[(G) * 8 + jj];                           \
                        if (dj < gd[G]) { gd[G] = dj; gp[G] = ((G) * 8 + jj) * 64 + lane; } \
                    }                                                         \
                }
                switch (gsel) {
                    case 0: KNN_RECOMP(0); break;
                    case 1: KNN_RECOMP(1); break;
                    case 2: KNN_RECOMP(2); break;
                    default: KNN_RECOMP(3); break;
                }
#undef KNN_RECOMP
            }
        }
        if (lane < KK) idxk[(size_t)mrow * KK + lane] = myidx;
    }
}

// ---------------------------------------------------------------------------
// Kernel 4: persistent-block fp16 MFMA MLP (layers 2+3) + max over K.
// (unchanged from round 12 — verified; 1024 thr / 16 waves)
// ---------------------------------------------------------------------------
#define SM_W2 0
#define SM_W3 32768
#define SM_H1 98304
#define SM_H2 114688
#define SM_B2 131072
#define SM_B3 131584
#define SM_TOTAL 132608

__global__ __launch_bounds__(1024, 1) void k_mlp(const _Float16* __restrict__ Pp,
                                                 const float* __restrict__ Qp,
                                                 const int* __restrict__ idxk,
                                                 const float* __restrict__ w2,
                                                 const float* __restrict__ b2,
                                                 const float* __restrict__ w3,
                                                 const float* __restrict__ b3,
                                                 float* __restrict__ out_feat) {
    extern __shared__ char smem[];
    int tid = threadIdx.x;
    int bid = blockIdx.x;                  // 0..255

    for (int i = tid; i < 128 * 128; i += 1024) {
        int n = i & 127, kk = i >> 7;
        _Float16 v = (_Float16)w2[kk * 128 + n];
        *(_Float16*)(smem + SM_W2 + n * 256 + ((2 * kk) ^ ((n & 7) << 4))) = v;
    }
    for (int i = tid; i < 256 * 128; i += 1024) {
        int n = i & 255, kk = i >> 8;
        _Float16 v = (_Float16)w3[kk * 256 + n];
        *(_Float16*)(smem + SM_W3 + n * 256 + ((2 * kk) ^ ((n & 7) << 4))) = v;
    }
    if (tid < 128) *(float*)(smem + SM_B2 + tid * 4) = b2[tid];
    if (tid < 256) *(float*)(smem + SM_B3 + tid * 4) = b3[tid];
    __syncthreads();

    int lane = tid & 63;
    int w = tid >> 6;                      // 0..15
    int wm = w >> 3, wn = w & 7;           // 2 anchors x 8 col-groups
    int l15 = lane & 15, g = lane >> 4;
    int hswz = (l15 & 7) << 4;

    const f32x4 zero4 = {0.f, 0.f, 0.f, 0.f};

    for (int c = 0; c < 32; ++c) {
        int a0 = bid * 64 + c * 2;
        int bt = a0 >> 9;

        // ---- build h1: 64 rows x 16 segments of 8 fp16, one f16x8/thread ----
        {
            int r = tid >> 4, seg = tid & 15;
            int arow = a0 + (r >> 5);
            int kidx = r & 31;
            int nk = idxk[(size_t)arow * KK + kidx];
            const _Float16* ps = Pp + ((size_t)(bt * NN + nk)) * 128 + seg * 8;
            const float* qs = Qp + (size_t)arow * 128 + seg * 8;
            int rowbase = SM_H1 + r * 256;
            int swz = (r & 7) << 4;
            f16x8 pv = *(const f16x8*)ps;
            f32x4 q0 = *(const f32x4*)qs;
            f32x4 q1 = *(const f32x4*)(qs + 4);
            f16x8 hv;
#pragma unroll
            for (int j = 0; j < 4; ++j) hv[j] = (_Float16)fmaxf((float)pv[j] + q0[j], 0.f);
#pragma unroll
            for (int j = 0; j < 4; ++j) hv[4 + j] = (_Float16)fmaxf((float)pv[4 + j] + q1[j], 0.f);
            *(f16x8*)(smem + rowbase + ((seg * 16) ^ swz)) = hv;
        }
        __syncthreads();

        // ---- layer 2: wave tile 32 rows x 16 cols ----
        f32x4 acc2[2];
#pragma unroll
        for (int m = 0; m < 2; ++m) acc2[m] = zero4;

#pragma unroll
        for (int ks = 0; ks < 4; ++ks) {
            int kbyte = ks * 64 + g * 16;
            f16x8 af[2], bf;
#pragma unroll
            for (int m = 0; m < 2; ++m) {
                int row = wm * 32 + m * 16 + l15;
                af[m] = *(const f16x8*)(smem + SM_H1 + row * 256 + (kbyte ^ hswz));
            }
            {
                int col = wn * 16 + l15;
                bf = *(const f16x8*)(smem + SM_W2 + col * 256 + (kbyte ^ hswz));
            }
#pragma unroll
            for (int m = 0; m < 2; ++m)
                acc2[m] = __builtin_amdgcn_mfma_f32_16x16x32_f16(af[m], bf, acc2[m], 0, 0, 0);
        }
#pragma unroll
        for (int m = 0; m < 2; ++m) {
            int col = wn * 16 + l15;
            float bb = *(const float*)(smem + SM_B2 + col * 4);
#pragma unroll
            for (int r = 0; r < 4; ++r) {
                int row = wm * 32 + m * 16 + g * 4 + r;
                float v = fmaxf(acc2[m][r] + bb, 0.f);
                *(_Float16*)(smem + SM_H2 + row * 256 + ((2 * col) ^ ((row & 7) << 4))) = (_Float16)v;
            }
        }
        __syncthreads();

        // ---- layer 3: wave tile 32 rows x 32 cols; max over K fused ----
        f32x4 acc3[2][2];
#pragma unroll
        for (int m = 0; m < 2; ++m)
#pragma unroll
            for (int n = 0; n < 2; ++n) acc3[m][n] = zero4;

#pragma unroll
        for (int ks = 0; ks < 4; ++ks) {
            int kbyte = ks * 64 + g * 16;
            f16x8 af[2], bf[2];
#pragma unroll
            for (int m = 0; m < 2; ++m) {
                int row = wm * 32 + m * 16 + l15;
                af[m] = *(const f16x8*)(smem + SM_H2 + row * 256 + (kbyte ^ hswz));
            }
#pragma unroll
            for (int n = 0; n < 2; ++n) {
                int col = wn * 32 + n * 16 + l15;
                bf[n] = *(const f16x8*)(smem + SM_W3 + col * 256 + (kbyte ^ hswz));
            }
#pragma unroll
            for (int m = 0; m < 2; ++m)
#pragma unroll
                for (int n = 0; n < 2; ++n)
                    acc3[m][n] = __builtin_amdgcn_mfma_f32_16x16x32_f16(af[m], bf[n], acc3[m][n], 0, 0, 0);
        }
#pragma unroll
        for (int n = 0; n < 2; ++n) {
            int col = wn * 32 + n * 16 + l15;
            float s = acc3[0][n][0];
#pragma unroll
            for (int r = 1; r < 4; ++r) s = fmaxf(s, acc3[0][n][r]);
#pragma unroll
            for (int r = 0; r < 4; ++r) s = fmaxf(s, acc3[1][n][r]);
            s = fmaxf(s, __shfl_xor(s, 16));
            s = fmaxf(s, __shfl_xor(s, 32));
            if (g == 0) {
                float bb = *(const float*)(smem + SM_B3 + col * 4);
                out_feat[(size_t)(a0 + wm) * H3DIM + col] = fmaxf(s + bb, 0.f);
            }
        }
        __syncthreads();
    }
}

// ---------------------------------------------------------------------------
extern "C" void kernel_launch(void* const* d_in, const int* in_sizes, int n_in,
                              void* d_out, int out_size, void* d_ws, size_t ws_size,
                              hipStream_t stream) {
    const float* xyzs  = (const float*)d_in[0];
    const float* feats = (const float*)d_in[1];
    const float* w1 = (const float*)d_in[2];
    const float* b1 = (const float*)d_in[3];
    const float* w2 = (const float*)d_in[4];
    const float* b2 = (const float*)d_in[5];
    const float* w3 = (const float*)d_in[6];
    const float* b3 = (const float*)d_in[7];

    float* out_anchor = (float*)d_out;
    float* out_feat = out_anchor + (size_t)BB * TT * MM * 3;

    char* ws = (char*)d_ws;
    int* fps_idx = (int*)ws;                                   // 64 KB
    int* idxk = (int*)(ws + 65536);                            // 2 MB
    _Float16* Pp = (_Float16*)(ws + 65536 + 2097152);          // B*T*N*128 fp16 = 16 MB
    float* Qp = (float*)(ws + 65536 + 2097152 + 16777216);     // B*T*M*128 fp32 = 8 MB
    if (ws_size < (size_t)(65536 + 2097152 + 16777216) + (size_t)BB * TT * MM * 128 * 4)
        return;

    (void)hipFuncSetAttribute((const void*)k_fps_pp, hipFuncAttributeMaxDynamicSharedMemorySize, FPP_LDS);
    k_fps_pp<<<BB * TT + BB * TT * NN / 64, 256, FPP_LDS, stream>>>(xyzs, feats, w1, fps_idx, Pp);
    k_knn<<<BB * TT * 64, 256, 0, stream>>>(xyzs, fps_idx, idxk);
    k_qp<<<BB * TT * MM / 64, 256, 0, stream>>>(xyzs, feats, w1, b1, fps_idx, Qp, out_anchor);

    (void)hipFuncSetAttribute((const void*)k_mlp, hipFuncAttributeMaxDynamicSharedMemorySize, SM_TOTAL);
    k_mlp<<<256, 1024, SM_TOTAL, stream>>>(Pp, Qp, idxk, w2, b2, w3, b3, out_feat);
}

// Round 18
// 515.898 us; speedup vs baseline: 1.1095x; 1.0258x over previous
//
#include <hip/hip_runtime.h>

// Problem constants (B=4, T=8, N=2048, C=64)
#define BB 4
#define TT 8
#define NN 2048
#define CC 64
#define MM 512           // N / SPATIAL_STRIDE
#define KK 32
#define H3DIM 256
#define RAD2 0.25f
#define FINF 3.4e38f

typedef _Float16 f16x8 __attribute__((ext_vector_type(8)));
typedef _Float16 f16x4 __attribute__((ext_vector_type(4)));
typedef float f32x4 __attribute__((ext_vector_type(4)));

// ---------------------------------------------------------------------------
// f32 DPP wave-64 max tree (row_shr 1/2/4/8 + row_bcast15/31, result lane 63).
// HW-validated rounds 2-15.
// ---------------------------------------------------------------------------
template <int CTRL>
__device__ __forceinline__ float dpp_max_step(float x) {
    int xi = __builtin_bit_cast(int, x);
    int yi = __builtin_amdgcn_update_dpp(xi, xi, CTRL, 0xf, 0xf, false);
    return fmaxf(x, __builtin_bit_cast(float, yi));
}
__device__ __forceinline__ float wave_max64(float x) {
    x = dpp_max_step<0x111>(x);
    x = dpp_max_step<0x112>(x);
    x = dpp_max_step<0x114>(x);
    x = dpp_max_step<0x118>(x);
    x = dpp_max_step<0x142>(x);
    x = dpp_max_step<0x143>(x);
    return __builtin_bit_cast(float, __builtin_amdgcn_readlane(__builtin_bit_cast(int, x), 63));
}
// Packed u64 DPP min (validated rounds 8-15 in k_knn).
template <int CTRL>
__device__ __forceinline__ unsigned long long dpp_minkey_step(unsigned long long k) {
    int lo = (int)(unsigned)k;
    int hi = (int)(unsigned)(k >> 32);
    int slo = __builtin_amdgcn_update_dpp(lo, lo, CTRL, 0xf, 0xf, false);
    int shi = __builtin_amdgcn_update_dpp(hi, hi, CTRL, 0xf, 0xf, false);
    unsigned long long s = ((unsigned long long)(unsigned)shi << 32) | (unsigned)slo;
    return s < k ? s : k;
}
__device__ __forceinline__ unsigned long long wave_minkey(unsigned long long k) {
    k = dpp_minkey_step<0x111>(k);
    k = dpp_minkey_step<0x112>(k);
    k = dpp_minkey_step<0x114>(k);
    k = dpp_minkey_step<0x118>(k);
    k = dpp_minkey_step<0x142>(k);
    k = dpp_minkey_step<0x143>(k);
    int lo = __builtin_amdgcn_readlane((int)(unsigned)k, 63);
    int hi = __builtin_amdgcn_readlane((int)(unsigned)(k >> 32), 63);
    return ((unsigned long long)(unsigned)hi << 32) | (unsigned)lo;
}

// ---------------------------------------------------------------------------
// Fused kernel 1: FPS (blocks 0..31) + P' (blocks 32..1055).
// (unchanged from round 11 — verified, 245 us)
// ---------------------------------------------------------------------------
#define FPP_LDS 52224   // max(fps: 24640, pp: 68*128*4 + 64*68*4 = 52224)

__global__ __launch_bounds__(256) void k_fps_pp(const float* __restrict__ xyzs,
                                                const float* __restrict__ feats,
                                                const float* __restrict__ w1,
                                                int* __restrict__ fps_idx,
                                                _Float16* __restrict__ Pp) {
    extern __shared__ char fsm[];
    int tid = threadIdx.x;

    if (blockIdx.x < BB * TT) {
        // ------------------------- FPS branch (round-5 verbatim) -----------
        float* sx = (float*)fsm;
        float* sy = sx + NN;
        float* sz = sy + NN;
        float* pd = sz + NN;            // [2][4]
        int* pi = (int*)(pd + 8);       // [2][4]
        int bt = blockIdx.x;
        int lane = tid & 63, w = tid >> 6;
        const float* src = xyzs + (size_t)bt * NN * 3;
        for (int i = tid; i < NN; i += 256) {
            sx[i] = src[i * 3 + 0];
            sy[i] = src[i * 3 + 1];
            sz[i] = src[i * 3 + 2];
        }
        __syncthreads();

        float px[8], py[8], pz[8], dist[8];
#pragma unroll
        for (int j = 0; j < 8; ++j) {
            int p = tid * 8 + j;
            px[j] = sx[p]; py[j] = sy[p]; pz[j] = sz[p];
            dist[j] = 1e10f;
        }

        int cur = 0;
        if (tid == 0) fps_idx[bt * MM + 0] = 0;
        int pbase = tid * 8;

        for (int it = 1; it < MM; ++it) {
            float cx = sx[cur], cy = sy[cur], cz = sz[cur];   // broadcast reads
            float bestd = -1.0f;
            int bestp = 0;
#pragma unroll
            for (int j = 0; j < 8; ++j) {
                float dx = px[j] - cx, dy = py[j] - cy, dz = pz[j] - cz;
                float d = dx * dx + dy * dy + dz * dz;
                float nd = fminf(dist[j], d);
                dist[j] = nd;
                if (nd > bestd) { bestd = nd; bestp = pbase + j; }  // strict > keeps smallest j
            }
            float wmax = wave_max64(bestd);
            unsigned long long mask = __ballot(bestd == wmax);
            int wl = __ffsll(mask) - 1;
            int wbp = __builtin_amdgcn_readlane(bestp, wl);
            if (lane == 0) { pd[(it & 1) * 4 + w] = wmax; pi[(it & 1) * 4 + w] = wbp; }
            __syncthreads();
            float bd = pd[(it & 1) * 4 + 0];
            int bp = pi[(it & 1) * 4 + 0];
#pragma unroll
            for (int q = 1; q < 4; ++q) {
                float d2 = pd[(it & 1) * 4 + q];
                int p2 = pi[(it & 1) * 4 + q];
                if (d2 > bd) { bd = d2; bp = p2; }   // strict > : earlier wave wins ties
            }
            cur = bp;
            if (tid == 0) fps_idx[bt * MM + it] = cur;
        }
    } else {
        // ------------------------- P' branch (round-9 k_pp verbatim) -------
        float* sw = (float*)fsm;              // 68*128
        float* sin_ = sw + 68 * 128;          // 64*68
        for (int i = tid; i < 68 * 128; i += 256) {
            int r = i >> 7, c = i & 127;
            float v = 0.f;
            if (r < 64) v = w1[r * 128 + c];
            else if (r < 67) v = w1[(128 + r - 64) * 128 + c];
            sw[i] = v;
        }
        int row0 = (blockIdx.x - BB * TT) * 64;
        int bt = row0 >> 11;
        int b = bt >> 3, t = bt & 7;
        int tn = (t + 1 < TT) ? (t + 1) : (TT - 1);
        size_t nbase = (size_t)(b * TT + tn) * NN + (row0 & (NN - 1));
        const float* fsrc = feats + nbase * CC;
        const float* xsrc = xyzs + nbase * 3;
        for (int i = tid; i < 1024; i += 256) {
            float4 v = ((const float4*)fsrc)[i];
            int r = i >> 4, c = (i & 15) * 4;
            *(float4*)&sin_[r * 68 + c] = v;
        }
        if (tid < 192) {
            int r = tid / 3, c = tid - r * 3;
            sin_[r * 68 + 64 + c] = xsrc[tid];
        }
        if (tid < 64) sin_[tid * 68 + 67] = 0.f;
        __syncthreads();

        int rowg = tid >> 5, colg = tid & 31;
        float4 acc[8];
#pragma unroll
        for (int i = 0; i < 8; ++i) acc[i] = make_float4(0.f, 0.f, 0.f, 0.f);
        for (int k = 0; k < 68; k += 4) {
            float4 a4[8], b4[4];
#pragma unroll
            for (int i = 0; i < 8; ++i) a4[i] = *(const float4*)&sin_[(rowg * 8 + i) * 68 + k];
#pragma unroll
            for (int kk = 0; kk < 4; ++kk) b4[kk] = *(const float4*)&sw[(k + kk) * 128 + colg * 4];
#pragma unroll
            for (int i = 0; i < 8; ++i) {
#pragma unroll
                for (int kk = 0; kk < 4; ++kk) {
                    float av = (kk == 0) ? a4[i].x : (kk == 1) ? a4[i].y : (kk == 2) ? a4[i].z : a4[i].w;
                    acc[i].x += av * b4[kk].x;
                    acc[i].y += av * b4[kk].y;
                    acc[i].z += av * b4[kk].z;
                    acc[i].w += av * b4[kk].w;
                }
            }
        }
#pragma unroll
        for (int i = 0; i < 8; ++i) {
            f16x4 h;
            h[0] = (_Float16)acc[i].x; h[1] = (_Float16)acc[i].y;
            h[2] = (_Float16)acc[i].z; h[3] = (_Float16)acc[i].w;
            *(f16x4*)&Pp[(size_t)(row0 + rowg * 8 + i) * 128 + colg * 4] = h;
        }
    }
}

// ---------------------------------------------------------------------------
// Kernel 2: exact stable top-K=32 nearest + radius filter.
// (unchanged from round 15 — verified; cached group-minima)
// ---------------------------------------------------------------------------
__global__ __launch_bounds__(256) void k_knn(const float* __restrict__ xyzs,
                                             const int* __restrict__ fps_idx,
                                             int* __restrict__ idxk) {
    __shared__ float sx[NN], sy[NN], sz[NN];
    int tid = threadIdx.x;
    int wave = tid >> 6, lane = tid & 63;
    int bt = blockIdx.x >> 6;              // 64 blocks per (b,t)
    int sub = blockIdx.x & 63;
    int b = bt >> 3, t = bt & 7;
    int tn = (t + 1 < TT) ? (t + 1) : (TT - 1);
    const float* src = xyzs + ((size_t)(b * TT + tn)) * NN * 3;
    for (int i = tid; i < NN; i += 256) {
        sx[i] = src[i * 3 + 0];
        sy[i] = src[i * 3 + 1];
        sz[i] = src[i * 3 + 2];
    }
    __syncthreads();

    for (int a = 0; a < 2; ++a) {
        int mrow = bt * MM + sub * 8 + wave * 2 + a;
        int aidx = fps_idx[mrow];
        const float* xs = xyzs + ((size_t)bt * NN + aidx) * 3;   // frame t itself
        float ax = xs[0], ay = xs[1], az = xs[2];
        float d[32];
#pragma unroll
        for (int j = 0; j < 32; ++j) {
            int p = j * 64 + lane;
            float dx = sx[p] - ax, dy = sy[p] - ay, dz = sz[p] - az;
            d[j] = dx * dx + dy * dy + dz * dz;
        }
        // initial full group scan
        float gd[4];
        int gp[4];
#pragma unroll
        for (int g = 0; g < 4; ++g) {
            gd[g] = d[g * 8];
            gp[g] = (g * 8) * 64 + lane;
#pragma unroll
            for (int jj = 1; jj < 8; ++jj) {
                float dj = d[g * 8 + jj];
                if (dj < gd[g]) { gd[g] = dj; gp[g] = (g * 8 + jj) * 64 + lane; }  // strict <
            }
        }

        int p0 = 0;
        int myidx = 0;
        for (int r = 0; r < KK; ++r) {
            bool u01 = gd[1] < gd[0], u23 = gd[3] < gd[2];
            float da = u01 ? gd[1] : gd[0], db = u23 ? gd[3] : gd[2];
            int pa = u01 ? gp[1] : gp[0], pb = u23 ? gp[3] : gp[2];
            bool uf = db < da;
            float bd = uf ? db : da;
            int bp = uf ? pb : pa;
            unsigned long long key =
                ((unsigned long long)(unsigned)__builtin_bit_cast(unsigned, bd) << 32) |
                (unsigned)bp;
            unsigned long long wkey = wave_minkey(key);
            int pstar = (int)(unsigned)wkey;
            float dstar = __builtin_bit_cast(float, (unsigned)(wkey >> 32));
            if (r == 0) { p0 = pstar; myidx = pstar; }
            int outp = (dstar <= RAD2) ? pstar : p0;   // radius replacement
            if (lane == r) myidx = outp;
            if (r < KK - 1) {
                int lanew = pstar & 63;                 // uniform (SGPR)
                int jw = pstar >> 6;                    // uniform slot 0..31
                int gsel = jw >> 3;                     // uniform group 0..3
                int jl = jw & 7;                        // uniform slot-in-group
                bool imw = (lane == lanew);
#define KNN_RECOMP(G)                                                         \
                {                                                             \
                    _Pragma("unroll")                                         \
                    for (int jj = 0; jj < 8; ++jj) {                          \
                        float dj = d[(G) * 8 + jj];                           \
                        dj = (imw && jj == jl) ? FINF : dj;                   \
                        d[(G) * 8 + jj] = dj;                                 \
                    }                                                         \
                    gd[G] = d[(G) * 8];                                       \
                    gp[G] = ((G) * 8) * 64 + lane;                            \
                    _Pragma("unroll")                                         \
                    for (int jj = 1; jj < 8; ++jj) {                          \
                        float dj = d[(G) * 8 + jj];                           \
                        if (dj < gd[G]) { gd[G] = dj; gp[G] = ((G) * 8 + jj) * 64 + lane; } \
                    }                                                         \
                }
                switch (gsel) {
                    case 0: KNN_RECOMP(0); break;
                    case 1: KNN_RECOMP(1); break;
                    case 2: KNN_RECOMP(2); break;
                    default: KNN_RECOMP(3); break;
                }
#undef KNN_RECOMP
            }
        }
        if (lane < KK) idxk[(size_t)mrow * KK + lane] = myidx;
    }
}

// ---------------------------------------------------------------------------
// Kernel 3: fused Q'(ex-k_qp, phase 0) + fp16 MFMA MLP (layers 2+3) + max.
// Phase 0 computes Q' + anchors for this block's OWN 64 anchors with the
// exact k_qp accumulation order (bit-identical), using LDS bytes 0..52736
// (overwritten by w2/w3 staging after a barrier). Qp round-trips via L2.
// ---------------------------------------------------------------------------
#define SM_W2 0
#define SM_W3 32768
#define SM_H1 98304
#define SM_H2 114688
#define SM_B2 131072
#define SM_B3 131584
#define SM_TOTAL 132608

__global__ __launch_bounds__(1024, 1) void k_mlp(const float* __restrict__ xyzs,
                                                 const float* __restrict__ feats,
                                                 const float* __restrict__ w1,
                                                 const float* __restrict__ b1,
                                                 const int* __restrict__ fps_idx,
                                                 const _Float16* __restrict__ Pp,
                                                 float* __restrict__ Qp,
                                                 const int* __restrict__ idxk,
                                                 const float* __restrict__ w2,
                                                 const float* __restrict__ b2,
                                                 const float* __restrict__ w3,
                                                 const float* __restrict__ b3,
                                                 float* __restrict__ out_anchor,
                                                 float* __restrict__ out_feat) {
    extern __shared__ char smem[];
    int tid = threadIdx.x;
    int bid = blockIdx.x;                  // 0..255

    // ---- phase 0: Q' + anchors for this block's 64 anchors (ex-k_qp) ----
    {
        float* qsw = (float*)smem;             // 68*128 f32
        float* qsin = qsw + 68 * 128;          // 64*68 f32
        float* qsb = qsin + 64 * 68;           // 128 f32
        for (int i = tid; i < 68 * 128; i += 1024) {
            int r = i >> 7, c = i & 127;
            float v = 0.f;
            if (r < 64) v = w1[(64 + r) * 128 + c];
            else if (r < 67) v = w1[(128 + r - 64) * 128 + c];
            qsw[i] = v;
        }
        if (tid < 128) qsb[tid] = b1[tid];
        int row0 = bid * 64;
        int bt0 = row0 >> 9;
        size_t fbase = (size_t)bt0 * NN;
        {
            int r = tid >> 4, seg = tid & 15;  // 64 rows x 16 float4 segs
            int aidx = fps_idx[row0 + r];
            const float4* fr = (const float4*)(feats + (fbase + aidx) * CC);
            float4 v = fr[seg];
            *(float4*)&qsin[r * 68 + seg * 4] = v;
        }
        if (tid < 64) {
            int aidx = fps_idx[row0 + tid];
            const float* xs = xyzs + (fbase + aidx) * 3;
            float x = xs[0], y = xs[1], z = xs[2];
            qsin[tid * 68 + 64] = -x;
            qsin[tid * 68 + 65] = -y;
            qsin[tid * 68 + 66] = -z;
            qsin[tid * 68 + 67] = 0.f;
            out_anchor[(size_t)(row0 + tid) * 3 + 0] = x;
            out_anchor[(size_t)(row0 + tid) * 3 + 1] = y;
            out_anchor[(size_t)(row0 + tid) * 3 + 2] = z;
        }
        __syncthreads();

        int rowg = tid >> 5, colg = tid & 31;  // 32 row-groups x 2 rows; 32 col-groups x 4
        float4 bias = *(const float4*)&qsb[colg * 4];
        float4 acc[2];
#pragma unroll
        for (int i = 0; i < 2; ++i) acc[i] = bias;
        for (int k = 0; k < 68; k += 4) {
            float4 a4[2], b4[4];
#pragma unroll
            for (int i = 0; i < 2; ++i) a4[i] = *(const float4*)&qsin[(rowg * 2 + i) * 68 + k];
#pragma unroll
            for (int kk = 0; kk < 4; ++kk) b4[kk] = *(const float4*)&qsw[(k + kk) * 128 + colg * 4];
#pragma unroll
            for (int i = 0; i < 2; ++i) {
#pragma unroll
                for (int kk = 0; kk < 4; ++kk) {
                    float av = (kk == 0) ? a4[i].x : (kk == 1) ? a4[i].y : (kk == 2) ? a4[i].z : a4[i].w;
                    acc[i].x += av * b4[kk].x;
                    acc[i].y += av * b4[kk].y;
                    acc[i].z += av * b4[kk].z;
                    acc[i].w += av * b4[kk].w;
                }
            }
        }
#pragma unroll
        for (int i = 0; i < 2; ++i)
            *(float4*)&Qp[(size_t)(row0 + rowg * 2 + i) * 128 + colg * 4] = acc[i];
    }
    __syncthreads();   // Qp written (drained before barrier); LDS free for weights

    // ---- one-time weight staging (unchanged) ----
    for (int i = tid; i < 128 * 128; i += 1024) {
        int n = i & 127, kk = i >> 7;
        _Float16 v = (_Float16)w2[kk * 128 + n];
        *(_Float16*)(smem + SM_W2 + n * 256 + ((2 * kk) ^ ((n & 7) << 4))) = v;
    }
    for (int i = tid; i < 256 * 128; i += 1024) {
        int n = i & 255, kk = i >> 8;
        _Float16 v = (_Float16)w3[kk * 256 + n];
        *(_Float16*)(smem + SM_W3 + n * 256 + ((2 * kk) ^ ((n & 7) << 4))) = v;
    }
    if (tid < 128) *(float*)(smem + SM_B2 + tid * 4) = b2[tid];
    if (tid < 256) *(float*)(smem + SM_B3 + tid * 4) = b3[tid];
    __syncthreads();

    int lane = tid & 63;
    int w = tid >> 6;                      // 0..15
    int wm = w >> 3, wn = w & 7;           // 2 anchors x 8 col-groups
    int l15 = lane & 15, g = lane >> 4;
    int hswz = (l15 & 7) << 4;

    const f32x4 zero4 = {0.f, 0.f, 0.f, 0.f};

    for (int c = 0; c < 32; ++c) {
        int a0 = bid * 64 + c * 2;
        int bt = a0 >> 9;

        // ---- build h1: 64 rows x 16 segments of 8 fp16, one f16x8/thread ----
        {
            int r = tid >> 4, seg = tid & 15;
            int arow = a0 + (r >> 5);
            int kidx = r & 31;
            int nk = idxk[(size_t)arow * KK + kidx];
            const _Float16* ps = Pp + ((size_t)(bt * NN + nk)) * 128 + seg * 8;
            const float* qs = Qp + (size_t)arow * 128 + seg * 8;
            int rowbase = SM_H1 + r * 256;
            int swz = (r & 7) << 4;
            f16x8 pv = *(const f16x8*)ps;
            f32x4 q0 = *(const f32x4*)qs;
            f32x4 q1 = *(const f32x4*)(qs + 4);
            f16x8 hv;
#pragma unroll
            for (int j = 0; j < 4; ++j) hv[j] = (_Float16)fmaxf((float)pv[j] + q0[j], 0.f);
#pragma unroll
            for (int j = 0; j < 4; ++j) hv[4 + j] = (_Float16)fmaxf((float)pv[4 + j] + q1[j], 0.f);
            *(f16x8*)(smem + rowbase + ((seg * 16) ^ swz)) = hv;
        }
        __syncthreads();

        // ---- layer 2: wave tile 32 rows x 16 cols ----
        f32x4 acc2[2];
#pragma unroll
        for (int m = 0; m < 2; ++m) acc2[m] = zero4;

#pragma unroll
        for (int ks = 0; ks < 4; ++ks) {
            int kbyte = ks * 64 + g * 16;
            f16x8 af[2], bf;
#pragma unroll
            for (int m = 0; m < 2; ++m) {
                int row = wm * 32 + m * 16 + l15;
                af[m] = *(const f16x8*)(smem + SM_H1 + row * 256 + (kbyte ^ hswz));
            }
            {
                int col = wn * 16 + l15;
                bf = *(const f16x8*)(smem + SM_W2 + col * 256 + (kbyte ^ hswz));
            }
#pragma unroll
            for (int m = 0; m < 2; ++m)
                acc2[m] = __builtin_amdgcn_mfma_f32_16x16x32_f16(af[m], bf, acc2[m], 0, 0, 0);
        }
#pragma unroll
        for (int m = 0; m < 2; ++m) {
            int col = wn * 16 + l15;
            float bb = *(const float*)(smem + SM_B2 + col * 4);
#pragma unroll
            for (int r = 0; r < 4; ++r) {
                int row = wm * 32 + m * 16 + g * 4 + r;
                float v = fmaxf(acc2[m][r] + bb, 0.f);
                *(_Float16*)(smem + SM_H2 + row * 256 + ((2 * col) ^ ((row & 7) << 4))) = (_Float16)v;
            }
        }
        __syncthreads();

        // ---- layer 3: wave tile 32 rows x 32 cols; max over K fused ----
        f32x4 acc3[2][2];
#pragma unroll
        for (int m = 0; m < 2; ++m)
#pragma unroll
            for (int n = 0; n < 2; ++n) acc3[m][n] = zero4;

#pragma unroll
        for (int ks = 0; ks < 4; ++ks) {
            int kbyte = ks * 64 + g * 16;
            f16x8 af[2], bf[2];
#pragma unroll
            for (int m = 0; m < 2; ++m) {
                int row = wm * 32 + m * 16 + l15;
                af[m] = *(const f16x8*)(smem + SM_H2 + row * 256 + (kbyte ^ hswz));
            }
#pragma unroll
            for (int n = 0; n < 2; ++n) {
                int col = wn * 32 + n * 16 + l15;
                bf[n] = *(const f16x8*)(smem + SM_W3 + col * 256 + (kbyte ^ hswz));
            }
#pragma unroll
            for (int m = 0; m < 2; ++m)
#pragma unroll
                for (int n = 0; n < 2; ++n)
                    acc3[m][n] = __builtin_amdgcn_mfma_f32_16x16x32_f16(af[m], bf[n], acc3[m][n], 0, 0, 0);
        }
#pragma unroll
        for (int n = 0; n < 2; ++n) {
            int col = wn * 32 + n * 16 + l15;
            float s = acc3[0][n][0];
#pragma unroll
            for (int r = 1; r < 4; ++r) s = fmaxf(s, acc3[0][n][r]);
#pragma unroll
            for (int r = 0; r < 4; ++r) s = fmaxf(s, acc3[1][n][r]);
            s = fmaxf(s, __shfl_xor(s, 16));
            s = fmaxf(s, __shfl_xor(s, 32));
            if (g == 0) {
                float bb = *(const float*)(smem + SM_B3 + col * 4);
                out_feat[(size_t)(a0 + wm) * H3DIM + col] = fmaxf(s + bb, 0.f);
            }
        }
        __syncthreads();
    }
}

// ---------------------------------------------------------------------------
extern "C" void kernel_launch(void* const* d_in, const int* in_sizes, int n_in,
                              void* d_out, int out_size, void* d_ws, size_t ws_size,
                              hipStream_t stream) {
    const float* xyzs  = (const float*)d_in[0];
    const float* feats = (const float*)d_in[1];
    const float* w1 = (const float*)d_in[2];
    const float* b1 = (const float*)d_in[3];
    const float* w2 = (const float*)d_in[4];
    const float* b2 = (const float*)d_in[5];
    const float* w3 = (const float*)d_in[6];
    const float* b3 = (const float*)d_in[7];

    float* out_anchor = (float*)d_out;
    float* out_feat = out_anchor + (size_t)BB * TT * MM * 3;

    char* ws = (char*)d_ws;
    int* fps_idx = (int*)ws;                                   // 64 KB
    int* idxk = (int*)(ws + 65536);                            // 2 MB
    _Float16* Pp = (_Float16*)(ws + 65536 + 2097152);          // B*T*N*128 fp16 = 16 MB
    float* Qp = (float*)(ws + 65536 + 2097152 + 16777216);     // B*T*M*128 fp32 = 8 MB
    if (ws_size < (size_t)(65536 + 2097152 + 16777216) + (size_t)BB * TT * MM * 128 * 4)
        return;

    (void)hipFuncSetAttribute((const void*)k_fps_pp, hipFuncAttributeMaxDynamicSharedMemorySize, FPP_LDS);
    k_fps_pp<<<BB * TT + BB * TT * NN / 64, 256, FPP_LDS, stream>>>(xyzs, feats, w1, fps_idx, Pp);
    k_knn<<<BB * TT * 64, 256, 0, stream>>>(xyzs, fps_idx, idxk);

    (void)hipFuncSetAttribute((const void*)k_mlp, hipFuncAttributeMaxDynamicSharedMemorySize, SM_TOTAL);
    k_mlp<<<256, 1024, SM_TOTAL, stream>>>(xyzs, feats, w1, b1, fps_idx, Pp, Qp, idxk,
                                           w2, b2, w3, b3, out_anchor, out_feat);
}

// Round 19
// 515.127 us; speedup vs baseline: 1.1112x; 1.0015x over previous
//
#include <hip/hip_runtime.h>

// Problem constants (B=4, T=8, N=2048, C=64)
#define BB 4
#define TT 8
#define NN 2048
#define CC 64
#define MM 512           // N / SPATIAL_STRIDE
#define KK 32
#define H3DIM 256
#define RAD2 0.25f
#define FINF 3.4e38f

typedef _Float16 f16x8 __attribute__((ext_vector_type(8)));
typedef _Float16 f16x4 __attribute__((ext_vector_type(4)));
typedef float f32x4 __attribute__((ext_vector_type(4)));

// ---------------------------------------------------------------------------
// f32 DPP wave-64 max tree (row_shr 1/2/4/8 + row_bcast15/31, result lane 63).
// HW-validated rounds 2-18.
// ---------------------------------------------------------------------------
template <int CTRL>
__device__ __forceinline__ float dpp_max_step(float x) {
    int xi = __builtin_bit_cast(int, x);
    int yi = __builtin_amdgcn_update_dpp(xi, xi, CTRL, 0xf, 0xf, false);
    return fmaxf(x, __builtin_bit_cast(float, yi));
}
__device__ __forceinline__ float wave_max64(float x) {
    x = dpp_max_step<0x111>(x);
    x = dpp_max_step<0x112>(x);
    x = dpp_max_step<0x114>(x);
    x = dpp_max_step<0x118>(x);
    x = dpp_max_step<0x142>(x);
    x = dpp_max_step<0x143>(x);
    return __builtin_bit_cast(float, __builtin_amdgcn_readlane(__builtin_bit_cast(int, x), 63));
}
// Packed u64 DPP min (validated rounds 8-18 in knn).
template <int CTRL>
__device__ __forceinline__ unsigned long long dpp_minkey_step(unsigned long long k) {
    int lo = (int)(unsigned)k;
    int hi = (int)(unsigned)(k >> 32);
    int slo = __builtin_amdgcn_update_dpp(lo, lo, CTRL, 0xf, 0xf, false);
    int shi = __builtin_amdgcn_update_dpp(hi, hi, CTRL, 0xf, 0xf, false);
    unsigned long long s = ((unsigned long long)(unsigned)shi << 32) | (unsigned)slo;
    return s < k ? s : k;
}
__device__ __forceinline__ unsigned long long wave_minkey(unsigned long long k) {
    k = dpp_minkey_step<0x111>(k);
    k = dpp_minkey_step<0x112>(k);
    k = dpp_minkey_step<0x114>(k);
    k = dpp_minkey_step<0x118>(k);
    k = dpp_minkey_step<0x142>(k);
    k = dpp_minkey_step<0x143>(k);
    int lo = __builtin_amdgcn_readlane((int)(unsigned)k, 63);
    int hi = __builtin_amdgcn_readlane((int)(unsigned)(k >> 32), 63);
    return ((unsigned long long)(unsigned)hi << 32) | (unsigned)lo;
}

// ---------------------------------------------------------------------------
// Fused kernel 1: FPS (blocks 0..31) + P' (blocks 32..1055).
// (unchanged from round 11 — verified, 245 us)
// ---------------------------------------------------------------------------
#define FPP_LDS 52224   // max(fps: 24640, pp: 68*128*4 + 64*68*4 = 52224)

__global__ __launch_bounds__(256) void k_fps_pp(const float* __restrict__ xyzs,
                                                const float* __restrict__ feats,
                                                const float* __restrict__ w1,
                                                int* __restrict__ fps_idx,
                                                _Float16* __restrict__ Pp) {
    extern __shared__ char fsm[];
    int tid = threadIdx.x;

    if (blockIdx.x < BB * TT) {
        // ------------------------- FPS branch (round-5 verbatim) -----------
        float* sx = (float*)fsm;
        float* sy = sx + NN;
        float* sz = sy + NN;
        float* pd = sz + NN;            // [2][4]
        int* pi = (int*)(pd + 8);       // [2][4]
        int bt = blockIdx.x;
        int lane = tid & 63, w = tid >> 6;
        const float* src = xyzs + (size_t)bt * NN * 3;
        for (int i = tid; i < NN; i += 256) {
            sx[i] = src[i * 3 + 0];
            sy[i] = src[i * 3 + 1];
            sz[i] = src[i * 3 + 2];
        }
        __syncthreads();

        float px[8], py[8], pz[8], dist[8];
#pragma unroll
        for (int j = 0; j < 8; ++j) {
            int p = tid * 8 + j;
            px[j] = sx[p]; py[j] = sy[p]; pz[j] = sz[p];
            dist[j] = 1e10f;
        }

        int cur = 0;
        if (tid == 0) fps_idx[bt * MM + 0] = 0;
        int pbase = tid * 8;

        for (int it = 1; it < MM; ++it) {
            float cx = sx[cur], cy = sy[cur], cz = sz[cur];   // broadcast reads
            float bestd = -1.0f;
            int bestp = 0;
#pragma unroll
            for (int j = 0; j < 8; ++j) {
                float dx = px[j] - cx, dy = py[j] - cy, dz = pz[j] - cz;
                float d = dx * dx + dy * dy + dz * dz;
                float nd = fminf(dist[j], d);
                dist[j] = nd;
                if (nd > bestd) { bestd = nd; bestp = pbase + j; }  // strict > keeps smallest j
            }
            float wmax = wave_max64(bestd);
            unsigned long long mask = __ballot(bestd == wmax);
            int wl = __ffsll(mask) - 1;
            int wbp = __builtin_amdgcn_readlane(bestp, wl);
            if (lane == 0) { pd[(it & 1) * 4 + w] = wmax; pi[(it & 1) * 4 + w] = wbp; }
            __syncthreads();
            float bd = pd[(it & 1) * 4 + 0];
            int bp = pi[(it & 1) * 4 + 0];
#pragma unroll
            for (int q = 1; q < 4; ++q) {
                float d2 = pd[(it & 1) * 4 + q];
                int p2 = pi[(it & 1) * 4 + q];
                if (d2 > bd) { bd = d2; bp = p2; }   // strict > : earlier wave wins ties
            }
            cur = bp;
            if (tid == 0) fps_idx[bt * MM + it] = cur;
        }
    } else {
        // ------------------------- P' branch (round-9 k_pp verbatim) -------
        float* sw = (float*)fsm;              // 68*128
        float* sin_ = sw + 68 * 128;          // 64*68
        for (int i = tid; i < 68 * 128; i += 256) {
            int r = i >> 7, c = i & 127;
            float v = 0.f;
            if (r < 64) v = w1[r * 128 + c];
            else if (r < 67) v = w1[(128 + r - 64) * 128 + c];
            sw[i] = v;
        }
        int row0 = (blockIdx.x - BB * TT) * 64;
        int bt = row0 >> 11;
        int b = bt >> 3, t = bt & 7;
        int tn = (t + 1 < TT) ? (t + 1) : (TT - 1);
        size_t nbase = (size_t)(b * TT + tn) * NN + (row0 & (NN - 1));
        const float* fsrc = feats + nbase * CC;
        const float* xsrc = xyzs + nbase * 3;
        for (int i = tid; i < 1024; i += 256) {
            float4 v = ((const float4*)fsrc)[i];
            int r = i >> 4, c = (i & 15) * 4;
            *(float4*)&sin_[r * 68 + c] = v;
        }
        if (tid < 192) {
            int r = tid / 3, c = tid - r * 3;
            sin_[r * 68 + 64 + c] = xsrc[tid];
        }
        if (tid < 64) sin_[tid * 68 + 67] = 0.f;
        __syncthreads();

        int rowg = tid >> 5, colg = tid & 31;
        float4 acc[8];
#pragma unroll
        for (int i = 0; i < 8; ++i) acc[i] = make_float4(0.f, 0.f, 0.f, 0.f);
        for (int k = 0; k < 68; k += 4) {
            float4 a4[8], b4[4];
#pragma unroll
            for (int i = 0; i < 8; ++i) a4[i] = *(const float4*)&sin_[(rowg * 8 + i) * 68 + k];
#pragma unroll
            for (int kk = 0; kk < 4; ++kk) b4[kk] = *(const float4*)&sw[(k + kk) * 128 + colg * 4];
#pragma unroll
            for (int i = 0; i < 8; ++i) {
#pragma unroll
                for (int kk = 0; kk < 4; ++kk) {
                    float av = (kk == 0) ? a4[i].x : (kk == 1) ? a4[i].y : (kk == 2) ? a4[i].z : a4[i].w;
                    acc[i].x += av * b4[kk].x;
                    acc[i].y += av * b4[kk].y;
                    acc[i].z += av * b4[kk].z;
                    acc[i].w += av * b4[kk].w;
                }
            }
        }
#pragma unroll
        for (int i = 0; i < 8; ++i) {
            f16x4 h;
            h[0] = (_Float16)acc[i].x; h[1] = (_Float16)acc[i].y;
            h[2] = (_Float16)acc[i].z; h[3] = (_Float16)acc[i].w;
            *(f16x4*)&Pp[(size_t)(row0 + rowg * 8 + i) * 128 + colg * 4] = h;
        }
    }
}

// ---------------------------------------------------------------------------
// Kernel 2: fused Q'(phase 0) + per-block KNN (phase 1, ex-k_knn verbatim
// per anchor, idxk in LDS) + fp16 MFMA MLP (layers 2+3) + max over K.
// LDS: phase0 Q' 52.7KB | phase1 cloud 24KB (same pool) | weights 129.5KB
// | sidx 8KB at fixed offset 132608 (survives all phases). 140800 B total.
// ---------------------------------------------------------------------------
#define SM_W2 0
#define SM_W3 32768
#define SM_H1 98304
#define SM_H2 114688
#define SM_B2 131072
#define SM_B3 131584
#define SM_IDX 132608
#define SM_TOTAL (132608 + 64 * KK * 4)   // 140800

__global__ __launch_bounds__(1024, 1) void k_mlp(const float* __restrict__ xyzs,
                                                 const float* __restrict__ feats,
                                                 const float* __restrict__ w1,
                                                 const float* __restrict__ b1,
                                                 const int* __restrict__ fps_idx,
                                                 const _Float16* __restrict__ Pp,
                                                 float* __restrict__ Qp,
                                                 const float* __restrict__ w2,
                                                 const float* __restrict__ b2,
                                                 const float* __restrict__ w3,
                                                 const float* __restrict__ b3,
                                                 float* __restrict__ out_anchor,
                                                 float* __restrict__ out_feat) {
    extern __shared__ char smem[];
    int tid = threadIdx.x;
    int bid = blockIdx.x;                  // 0..255
    int* sidx = (int*)(smem + SM_IDX);     // [64][KK]

    // ---- phase 0: Q' + anchors for this block's 64 anchors (verified r18) ----
    {
        float* qsw = (float*)smem;             // 68*128 f32
        float* qsin = qsw + 68 * 128;          // 64*68 f32
        float* qsb = qsin + 64 * 68;           // 128 f32
        for (int i = tid; i < 68 * 128; i += 1024) {
            int r = i >> 7, c = i & 127;
            float v = 0.f;
            if (r < 64) v = w1[(64 + r) * 128 + c];
            else if (r < 67) v = w1[(128 + r - 64) * 128 + c];
            qsw[i] = v;
        }
        if (tid < 128) qsb[tid] = b1[tid];
        int row0 = bid * 64;
        int bt0 = row0 >> 9;
        size_t fbase = (size_t)bt0 * NN;
        {
            int r = tid >> 4, seg = tid & 15;  // 64 rows x 16 float4 segs
            int aidx = fps_idx[row0 + r];
            const float4* fr = (const float4*)(feats + (fbase + aidx) * CC);
            float4 v = fr[seg];
            *(float4*)&qsin[r * 68 + seg * 4] = v;
        }
        if (tid < 64) {
            int aidx = fps_idx[row0 + tid];
            const float* xs = xyzs + (fbase + aidx) * 3;
            float x = xs[0], y = xs[1], z = xs[2];
            qsin[tid * 68 + 64] = -x;
            qsin[tid * 68 + 65] = -y;
            qsin[tid * 68 + 66] = -z;
            qsin[tid * 68 + 67] = 0.f;
            out_anchor[(size_t)(row0 + tid) * 3 + 0] = x;
            out_anchor[(size_t)(row0 + tid) * 3 + 1] = y;
            out_anchor[(size_t)(row0 + tid) * 3 + 2] = z;
        }
        __syncthreads();

        int rowg = tid >> 5, colg = tid & 31;
        float4 bias = *(const float4*)&qsb[colg * 4];
        float4 acc[2];
#pragma unroll
        for (int i = 0; i < 2; ++i) acc[i] = bias;
        for (int k = 0; k < 68; k += 4) {
            float4 a4[2], b4[4];
#pragma unroll
            for (int i = 0; i < 2; ++i) a4[i] = *(const float4*)&qsin[(rowg * 2 + i) * 68 + k];
#pragma unroll
            for (int kk = 0; kk < 4; ++kk) b4[kk] = *(const float4*)&qsw[(k + kk) * 128 + colg * 4];
#pragma unroll
            for (int i = 0; i < 2; ++i) {
#pragma unroll
                for (int kk = 0; kk < 4; ++kk) {
                    float av = (kk == 0) ? a4[i].x : (kk == 1) ? a4[i].y : (kk == 2) ? a4[i].z : a4[i].w;
                    acc[i].x += av * b4[kk].x;
                    acc[i].y += av * b4[kk].y;
                    acc[i].z += av * b4[kk].z;
                    acc[i].w += av * b4[kk].w;
                }
            }
        }
#pragma unroll
        for (int i = 0; i < 2; ++i)
            *(float4*)&Qp[(size_t)(bid * 64 + rowg * 2 + i) * 128 + colg * 4] = acc[i];
    }
    __syncthreads();

    // ---- phase 1: KNN for this block's 64 anchors (ex-k_knn, verbatim) ----
    {
        float* sx = (float*)smem;              // 2048 f32
        float* sy = sx + NN;
        float* sz = sy + NN;
        int row0 = bid * 64;
        int bt = row0 >> 9;
        int b = bt >> 3, t = bt & 7;
        int tn = (t + 1 < TT) ? (t + 1) : (TT - 1);
        const float* src = xyzs + ((size_t)(b * TT + tn)) * NN * 3;
        for (int i = tid; i < NN; i += 1024) {
            sx[i] = src[i * 3 + 0];
            sy[i] = src[i * 3 + 1];
            sz[i] = src[i * 3 + 2];
        }
        __syncthreads();

        int wave = tid >> 6, lane = tid & 63;
        for (int a = 0; a < 4; ++a) {
            int la = wave * 4 + a;             // local anchor 0..63
            int mrow = row0 + la;
            int aidx = fps_idx[mrow];
            const float* xs = xyzs + ((size_t)bt * NN + aidx) * 3;   // frame t itself
            float ax = xs[0], ay = xs[1], az = xs[2];
            float d[32];
#pragma unroll
            for (int j = 0; j < 32; ++j) {
                int p = j * 64 + lane;
                float dx = sx[p] - ax, dy = sy[p] - ay, dz = sz[p] - az;
                d[j] = dx * dx + dy * dy + dz * dz;
            }
            // initial full group scan
            float gd[4];
            int gp[4];
#pragma unroll
            for (int g = 0; g < 4; ++g) {
                gd[g] = d[g * 8];
                gp[g] = (g * 8) * 64 + lane;
#pragma unroll
                for (int jj = 1; jj < 8; ++jj) {
                    float dj = d[g * 8 + jj];
                    if (dj < gd[g]) { gd[g] = dj; gp[g] = (g * 8 + jj) * 64 + lane; }  // strict <
                }
            }

            int p0 = 0;
            int myidx = 0;
            for (int r = 0; r < KK; ++r) {
                bool u01 = gd[1] < gd[0], u23 = gd[3] < gd[2];
                float da = u01 ? gd[1] : gd[0], db = u23 ? gd[3] : gd[2];
                int pa = u01 ? gp[1] : gp[0], pb = u23 ? gp[3] : gp[2];
                bool uf = db < da;
                float bd = uf ? db : da;
                int bp = uf ? pb : pa;
                unsigned long long key =
                    ((unsigned long long)(unsigned)__builtin_bit_cast(unsigned, bd) << 32) |
                    (unsigned)bp;
                unsigned long long wkey = wave_minkey(key);
                int pstar = (int)(unsigned)wkey;
                float dstar = __builtin_bit_cast(float, (unsigned)(wkey >> 32));
                if (r == 0) { p0 = pstar; myidx = pstar; }
                int outp = (dstar <= RAD2) ? pstar : p0;   // radius replacement
                if (lane == r) myidx = outp;
                if (r < KK - 1) {
                    int lanew = pstar & 63;
                    int jw = pstar >> 6;
                    int gsel = jw >> 3;
                    int jl = jw & 7;
                    bool imw = (lane == lanew);
#define KNN_RECOMP(G)                                                         \
                    {                                                         \
                        _Pragma("unroll")                                     \
                        for (int jj = 0; jj < 8; ++jj) {                      \
                            float dj = d[(G) * 8 + jj];                       \
                            dj = (imw && jj == jl) ? FINF : dj;               \
                            d[(G) * 8 + jj] = dj;                             \
                        }                                                     \
                        gd[G] = d[(G) * 8];                                   \
                        gp[G] = ((G) * 8) * 64 + lane;                        \
                        _Pragma("unroll")                                     \
                        for (int jj = 1; jj < 8; ++jj) {                      \
                            float dj = d[(G) * 8 + jj];                       \
                            if (dj < gd[G]) { gd[G] = dj; gp[G] = ((G) * 8 + jj) * 64 + lane; } \
                        }                                                     \
                    }
                    switch (gsel) {
                        case 0: KNN_RECOMP(0); break;
                        case 1: KNN_RECOMP(1); break;
                        case 2: KNN_RECOMP(2); break;
                        default: KNN_RECOMP(3); break;
                    }
#undef KNN_RECOMP
                }
            }
            if (lane < KK) sidx[la * KK + lane] = myidx;
        }
    }
    __syncthreads();

    // ---- weight staging (unchanged) ----
    for (int i = tid; i < 128 * 128; i += 1024) {
        int n = i & 127, kk = i >> 7;
        _Float16 v = (_Float16)w2[kk * 128 + n];
        *(_Float16*)(smem + SM_W2 + n * 256 + ((2 * kk) ^ ((n & 7) << 4))) = v;
    }
    for (int i = tid; i < 256 * 128; i += 1024) {
        int n = i & 255, kk = i >> 8;
        _Float16 v = (_Float16)w3[kk * 256 + n];
        *(_Float16*)(smem + SM_W3 + n * 256 + ((2 * kk) ^ ((n & 7) << 4))) = v;
    }
    if (tid < 128) *(float*)(smem + SM_B2 + tid * 4) = b2[tid];
    if (tid < 256) *(float*)(smem + SM_B3 + tid * 4) = b3[tid];
    __syncthreads();

    int lane = tid & 63;
    int w = tid >> 6;                      // 0..15
    int wm = w >> 3, wn = w & 7;           // 2 anchors x 8 col-groups
    int l15 = lane & 15, g = lane >> 4;
    int hswz = (l15 & 7) << 4;

    const f32x4 zero4 = {0.f, 0.f, 0.f, 0.f};

    for (int c = 0; c < 32; ++c) {
        int a0 = bid * 64 + c * 2;
        int bt = a0 >> 9;

        // ---- build h1 (idx from LDS sidx) ----
        {
            int r = tid >> 4, seg = tid & 15;
            int la = c * 2 + (r >> 5);         // local anchor in block
            int kidx = r & 31;
            int nk = sidx[la * KK + kidx];
            const _Float16* ps = Pp + ((size_t)(bt * NN + nk)) * 128 + seg * 8;
            const float* qs = Qp + (size_t)(bid * 64 + la) * 128 + seg * 8;
            int rowbase = SM_H1 + r * 256;
            int swz = (r & 7) << 4;
            f16x8 pv = *(const f16x8*)ps;
            f32x4 q0 = *(const f32x4*)qs;
            f32x4 q1 = *(const f32x4*)(qs + 4);
            f16x8 hv;
#pragma unroll
            for (int j = 0; j < 4; ++j) hv[j] = (_Float16)fmaxf((float)pv[j] + q0[j], 0.f);
#pragma unroll
            for (int j = 0; j < 4; ++j) hv[4 + j] = (_Float16)fmaxf((float)pv[4 + j] + q1[j], 0.f);
            *(f16x8*)(smem + rowbase + ((seg * 16) ^ swz)) = hv;
        }
        __syncthreads();

        // ---- layer 2: wave tile 32 rows x 16 cols ----
        f32x4 acc2[2];
#pragma unroll
        for (int m = 0; m < 2; ++m) acc2[m] = zero4;

#pragma unroll
        for (int ks = 0; ks < 4; ++ks) {
            int kbyte = ks * 64 + g * 16;
            f16x8 af[2], bf;
#pragma unroll
            for (int m = 0; m < 2; ++m) {
                int row = wm * 32 + m * 16 + l15;
                af[m] = *(const f16x8*)(smem + SM_H1 + row * 256 + (kbyte ^ hswz));
            }
            {
                int col = wn * 16 + l15;
                bf = *(const f16x8*)(smem + SM_W2 + col * 256 + (kbyte ^ hswz));
            }
#pragma unroll
            for (int m = 0; m < 2; ++m)
                acc2[m] = __builtin_amdgcn_mfma_f32_16x16x32_f16(af[m], bf, acc2[m], 0, 0, 0);
        }
#pragma unroll
        for (int m = 0; m < 2; ++m) {
            int col = wn * 16 + l15;
            float bb = *(const float*)(smem + SM_B2 + col * 4);
#pragma unroll
            for (int r = 0; r < 4; ++r) {
                int row = wm * 32 + m * 16 + g * 4 + r;
                float v = fmaxf(acc2[m][r] + bb, 0.f);
                *(_Float16*)(smem + SM_H2 + row * 256 + ((2 * col) ^ ((row & 7) << 4))) = (_Float16)v;
            }
        }
        __syncthreads();

        // ---- layer 3: wave tile 32 rows x 32 cols; max over K fused ----
        f32x4 acc3[2][2];
#pragma unroll
        for (int m = 0; m < 2; ++m)
#pragma unroll
            for (int n = 0; n < 2; ++n) acc3[m][n] = zero4;

#pragma unroll
        for (int ks = 0; ks < 4; ++ks) {
            int kbyte = ks * 64 + g * 16;
            f16x8 af[2], bf[2];
#pragma unroll
            for (int m = 0; m < 2; ++m) {
                int row = wm * 32 + m * 16 + l15;
                af[m] = *(const f16x8*)(smem + SM_H2 + row * 256 + (kbyte ^ hswz));
            }
#pragma unroll
            for (int n = 0; n < 2; ++n) {
                int col = wn * 32 + n * 16 + l15;
                bf[n] = *(const f16x8*)(smem + SM_W3 + col * 256 + (kbyte ^ hswz));
            }
#pragma unroll
            for (int m = 0; m < 2; ++m)
#pragma unroll
                for (int n = 0; n < 2; ++n)
                    acc3[m][n] = __builtin_amdgcn_mfma_f32_16x16x32_f16(af[m], bf[n], acc3[m][n], 0, 0, 0);
        }
#pragma unroll
        for (int n = 0; n < 2; ++n) {
            int col = wn * 32 + n * 16 + l15;
            float s = acc3[0][n][0];
#pragma unroll
            for (int r = 1; r < 4; ++r) s = fmaxf(s, acc3[0][n][r]);
#pragma unroll
            for (int r = 0; r < 4; ++r) s = fmaxf(s, acc3[1][n][r]);
            s = fmaxf(s, __shfl_xor(s, 16));
            s = fmaxf(s, __shfl_xor(s, 32));
            if (g == 0) {
                float bb = *(const float*)(smem + SM_B3 + col * 4);
                out_feat[(size_t)(a0 + wm) * H3DIM + col] = fmaxf(s + bb, 0.f);
            }
        }
        __syncthreads();
    }
}

// ---------------------------------------------------------------------------
extern "C" void kernel_launch(void* const* d_in, const int* in_sizes, int n_in,
                              void* d_out, int out_size, void* d_ws, size_t ws_size,
                              hipStream_t stream) {
    const float* xyzs  = (const float*)d_in[0];
    const float* feats = (const float*)d_in[1];
    const float* w1 = (const float*)d_in[2];
    const float* b1 = (const float*)d_in[3];
    const float* w2 = (const float*)d_in[4];
    const float* b2 = (const float*)d_in[5];
    const float* w3 = (const float*)d_in[6];
    const float* b3 = (const float*)d_in[7];

    float* out_anchor = (float*)d_out;
    float* out_feat = out_anchor + (size_t)BB * TT * MM * 3;

    char* ws = (char*)d_ws;
    int* fps_idx = (int*)ws;                                   // 64 KB
    _Float16* Pp = (_Float16*)(ws + 65536 + 2097152);          // B*T*N*128 fp16 = 16 MB
    float* Qp = (float*)(ws + 65536 + 2097152 + 16777216);     // B*T*M*128 fp32 = 8 MB
    if (ws_size < (size_t)(65536 + 2097152 + 16777216) + (size_t)BB * TT * MM * 128 * 4)
        return;

    (void)hipFuncSetAttribute((const void*)k_fps_pp, hipFuncAttributeMaxDynamicSharedMemorySize, FPP_LDS);
    k_fps_pp<<<BB * TT + BB * TT * NN / 64, 256, FPP_LDS, stream>>>(xyzs, feats, w1, fps_idx, Pp);

    (void)hipFuncSetAttribute((const void*)k_mlp, hipFuncAttributeMaxDynamicSharedMemorySize, SM_TOTAL);
    k_mlp<<<256, 1024, SM_TOTAL, stream>>>(xyzs, feats, w1, b1, fps_idx, Pp, Qp,
                                           w2, b2, w3, b3, out_anchor, out_feat);
}